// Round 7
// baseline (243.681 us; speedup 1.0000x reference)
//
#include <hip/hip_runtime.h>

// PointTransformerLayer fused kernel (MI355X / gfx950) — round 17
//
// Math:
//   relu1 = relu(aI_i - a_j)            aI = pos@pW1 + pb1, a = pos@pW1
//   S1    = relu1 @ W_pa  +  QA_i  +  KNA_j  + c      (decomposed, R15)
//     where W_pa = pW2@aW1 (K=64 MFMA),  QA_i = q_i@aW1  (f32, folded
//     into creg),  KNA_j = (-k_j)@aW1  (f32 table knat[t][j]),
//     c = ab1 + pb2@aW1.
//   H     = relu(S1);  simL2 = H @ (aW2*log2e)   (ab2 softmax-invariant)
//   rpe   = relu1 @ pW2 ; vv = (v+pb2)_j + rpe   (v folded into G3 C-op)
//   out_i[d] = sum_j 2^simL2 * vv / sum_j 2^simL2
//
// R17 = R16 + ka FULL-ITERATION register double-buffer:
//   R15 (issue top, consume same iter): stalls at CONSUMPTION (~150cy cover).
//   R16 (issue mid, consume next iter): stalls at the BARRIER — __syncthreads
//   emits s_waitcnt vmcnt(0), and only ~300-400cy (G2+G3+builder) precede it.
//   Both lost ~55us to one L2/L3 round-trip per iteration.
//   Fix: issue ka for tile n+1 at the TOP of iter n into a second register
//   set (kaN); the end-of-iter barrier drain then has the whole body
//   (~1500cy) of cover, and consumption happens next iteration post-drain.
//   Buffer rotation = 32 v_movs placed AFTER the barrier (values already
//   resident — the drain paid for them).  Math bit-identical (absmax 0.0625).
//   Pre-committed decision rule: if this lands >=140us the decomposition
//   line is dead -> R18 reverts to R14 (120.6us) for polish.

typedef float f32x4 __attribute__((ext_vector_type(4)));
typedef int   i32x8 __attribute__((ext_vector_type(8)));
using sh8 = __attribute__((ext_vector_type(8))) short;  // 8 bf16 (4 VGPRs)

static constexpr int NPTS = 1024;

#if __has_builtin(__builtin_amdgcn_exp2f)
#define EXP2(x) __builtin_amdgcn_exp2f(x)
#else
#define EXP2(x) exp2f(x)
#endif

// ---- ws layout (bytes) ----
static constexpr size_t BEXT_OFF = 0;        // W_pa frags: 2*16*64*8 bf16 = 32768 B (kc<2 only)
static constexpr size_t AW2F_OFF = 65536;    // fp8 frags: 16384 B
static constexpr size_t PW2F_OFF = 81920;    // 8192 B
static constexpr size_t CARR_OFF = 90112;    // 256 f32 = 1024 B
static constexpr size_t AI_OFF   = 91136;    // 1024*64 f32 (+pb1)      = 262144 B
static constexpr size_t AJ_OFF   = 353280;   // 1024*64 bf16            = 131072 B
static constexpr size_t VPT_OFF  = 484352;   // 64*1024 f32 (v+pb2, T)  = 262144 B
static constexpr size_t QA_OFF   = 746496;   // 1024*256 f32 (q@aW1)    = 1048576 B
static constexpr size_t KNAT_OFF = 1795072;  // 256*1024 f32 ((-k)@aW1, t-major)

__device__ __forceinline__ unsigned short f2b_rne(float f) {
    unsigned u = __float_as_uint(f);
    u += 0x7fffu + ((u >> 16) & 1u);
    return (unsigned short)(u >> 16);
}
// trunc-pack two f32 into bf16x2 — single v_perm_b32
__device__ __forceinline__ unsigned pk2(float lo, float hi) {
    return __builtin_amdgcn_perm(__float_as_uint(hi), __float_as_uint(lo), 0x07060302);
}
__device__ __forceinline__ float b2f(unsigned short s) {
    return __uint_as_float(((unsigned)s) << 16);
}
__device__ __forceinline__ unsigned char f2fp8(float v) {
    return (unsigned char)(__builtin_amdgcn_cvt_pk_fp8_f32(v, 0.f, 0, false) & 0xff);
}
__device__ __forceinline__ unsigned pk4fp8(float a, float b, float c, float d) {
    int r = __builtin_amdgcn_cvt_pk_fp8_f32(a, b, 0, false);
    r = __builtin_amdgcn_cvt_pk_fp8_f32(c, d, r, true);
    return (unsigned)r;
}
__device__ __forceinline__ i32x8 ld32B(const void* p) {
    const uint4 a = ((const uint4*)p)[0];
    const uint4 b = ((const uint4*)p)[1];
    i32x8 r;
    r[0] = a.x; r[1] = a.y; r[2] = a.z; r[3] = a.w;
    r[4] = b.x; r[5] = b.y; r[6] = b.z; r[7] = b.w;
    return r;
}

// ---------------- combined prep ----------------
// blocks: [0,64) bextf(W_pa) | [64,128) aw2f8 | [128,144) pw2f | 144 cArr
//         [145,401) points (v, aI, aJ; 4/blk) | [401,1425) QA (1 i/blk)
//         [1425,1681) KNAT (4 j/blk)
__global__ void prep_all(const float* __restrict__ x, const float* __restrict__ pos,
                         const float* __restrict__ Wq, const float* __restrict__ Wk,
                         const float* __restrict__ Wv, const float* __restrict__ pW1,
                         const float* __restrict__ pb1, const float* __restrict__ pW2,
                         const float* __restrict__ pb2, const float* __restrict__ aW1,
                         const float* __restrict__ ab1, const float* __restrict__ aW2,
                         unsigned short* __restrict__ bextf, unsigned char* __restrict__ aw2f8,
                         unsigned short* __restrict__ pw2f, float* __restrict__ cArr,
                         float* __restrict__ vPT, float* __restrict__ aI,
                         unsigned short* __restrict__ aJ, float* __restrict__ qa,
                         float* __restrict__ knat)
{
    __shared__ float s1[4][64];
    __shared__ float s2[4][64];
    const int b = blockIdx.x;
    if (b < 64) {
        // W_pa = pW2@aW1 frags, kc<2 (R2-verified layout)
        const int idx = b * 256 + threadIdx.x;  // < 16384
        const int k = idx >> 8, t = idx & 255;
        float s = 0.f;
        for (int d = 0; d < 64; ++d) s = fmaf(pW2[k * 64 + d], aW1[d * 256 + t], s);
        const int kc = k >> 5, kl = k & 31, qq = kl >> 3, e = kl & 7;
        const int ntg = t >> 4, tl = t & 15;
        bextf[(((size_t)(kc * 16 + ntg) * 64) + (qq * 16 + tl)) * 8 + e] = f2b_rne(s);
    } else if (b < 128) {
        // aW2*log2e fp8 frags for mfma_scale 16x16x128 (R9-verified)
        const int r = (b - 64) * 256 + threadIdx.x;  // < 16384
        const int e = r & 31, lane = (r >> 5) & 63, wsl = (r >> 11) & 3, kb = r >> 13;
        const int q = lane >> 4, dl = lane & 15;
        const int kp = kb * 128 + q * 32 + e;
        const int t = 64 * (kp >> 6) + 16 * (kp & 3) + ((kp >> 2) & 15);
        const int d = 16 * wsl + dl;
        aw2f8[r] = f2fp8(aW2[t * 64 + d] * 1.4426950408889634f);
    } else if (b < 144) {
        // pW2 frags (R2-verified)
        const int r = (b - 128) * 256 + threadIdx.x;  // < 4096
        const int k = r >> 6, d = r & 63;
        const int kc = k >> 5, kl = k & 31, qq = kl >> 3, e = kl & 7;
        const int nt = d >> 4, dl = d & 15;
        pw2f[(((size_t)(kc * 4 + nt) * 64) + (qq * 16 + dl)) * 8 + e] = f2b_rne(pW2[k * 64 + d]);
    } else if (b == 144) {
        const int t = threadIdx.x;
        float s = ab1[t];
        for (int d = 0; d < 64; ++d) s = fmaf(pb2[d], aW1[d * 256 + t], s);
        cArr[t] = s;
    } else if (b < 401) {
        // per-point prep: v, aI, aJ — 4 points per block
        const int t = threadIdx.x, sub = t >> 6, d = t & 63;
        const int i = (b - 145) * 4 + sub;
        s1[sub][d] = x[i * 64 + d];
        __syncthreads();
        float v = 0.f;
        for (int e = 0; e < 64; ++e) v = fmaf(s1[sub][e], Wv[e * 64 + d], v);
        const float a = pos[i * 2] * pW1[d] + pos[i * 2 + 1] * pW1[64 + d];
        vPT[d * NPTS + i] = v + pb2[d];
        aI[i * 64 + d] = a + pb1[d];
        aJ[i * 64 + d] = f2b_rne(a);
    } else if (b < 1425) {
        // QA[i][t] = (x_i@Wq)@aW1, f32
        const int i = b - 401, t = threadIdx.x;
        if (t < 64) s1[0][t] = x[i * 64 + t];
        __syncthreads();
        if (t < 64) {
            float s = 0.f;
            for (int e = 0; e < 64; ++e) s = fmaf(s1[0][e], Wq[e * 64 + t], s);
            s2[0][t] = s;
        }
        __syncthreads();
        float s = 0.f;
        for (int d = 0; d < 64; ++d) s = fmaf(s2[0][d], aW1[d * 256 + t], s);
        qa[(size_t)i * 256 + t] = s;
    } else {
        // KNAT[t][j] = -(x_j@Wk)@aW1, t-major, 4 j per block (float4 writes)
        const int j0 = (b - 1425) * 4, t = threadIdx.x;
        const int jj = t >> 6, d = t & 63;
        s1[jj][d] = x[(j0 + jj) * 64 + d];
        __syncthreads();
        float s = 0.f;
        for (int e = 0; e < 64; ++e) s = fmaf(s1[jj][e], Wk[e * 64 + d], s);
        s2[jj][d] = s;
        __syncthreads();
        float r0 = 0.f, r1 = 0.f, r2 = 0.f, r3 = 0.f;
        for (int d2 = 0; d2 < 64; ++d2) {
            const float wv = aW1[d2 * 256 + t];
            r0 = fmaf(s2[0][d2], wv, r0);
            r1 = fmaf(s2[1][d2], wv, r1);
            r2 = fmaf(s2[2][d2], wv, r2);
            r3 = fmaf(s2[3][d2], wv, r3);
        }
        float4 o = {-r0, -r1, -r2, -r3};
        *(float4*)(knat + (size_t)t * NPTS + j0) = o;
    }
}

// ---------------- main fused kernel: one block per query i, j-tile 32 ----------------
__global__ __launch_bounds__(256, 2) void ptl_main(
    const float* __restrict__ aI, const unsigned short* __restrict__ aJ,
    const float* __restrict__ vPT,
    const unsigned short* __restrict__ bextf, const unsigned char* __restrict__ aw2f8,
    const unsigned short* __restrict__ pw2f, const float* __restrict__ cArr,
    const float* __restrict__ qa, const float* __restrict__ knat,
    float* __restrict__ out)
{
    const int i    = blockIdx.x;
    const int tid  = threadIdx.x;
    const int w    = tid >> 6;    // wave: t-slice [64w,64w+64) for G1, d-slice [16w,16w+16) for G2/G3
    const int lane = tid & 63;
    const int m    = lane & 15;
    const int q    = lane >> 4;

    // double-buffered LDS: AfL 8 KB + Hs 17 KB = 25 KB
    __shared__ __align__(16) uint4 AfL[2][2][2][64];              // [buf][sub][kc][lane]
    __shared__ __align__(16) unsigned char Hs[2][2][16 * 272];    // fp8 H, stride 272

    // constant B fragments
    sh8 Bf[8];  // G1 (W_pa): [kc 0..1][nt 0..3]
#pragma unroll
    for (int kc = 0; kc < 2; ++kc)
#pragma unroll
        for (int nt = 0; nt < 4; ++nt)
            Bf[kc * 4 + nt] = *(const sh8*)(bextf + ((size_t)((kc * 16 + 4 * w + nt) * 64 + lane)) * 8);
    i32x8 W2f[2];  // G2 fp8: [kb 0..1], d-slice w
#pragma unroll
    for (int kb = 0; kb < 2; ++kb)
        W2f[kb] = ld32B(aw2f8 + ((size_t)((kb * 4 + w) * 64 + lane)) * 32);
    sh8 P2f[2];  // G3: [kc 0..1], d-slice w
#pragma unroll
    for (int kc = 0; kc < 2; ++kc)
        P2f[kc] = *(const sh8*)(pw2f + ((size_t)((kc * 4 + w) * 64 + lane)) * 8);

    float creg[4];  // c + QA_i  (both constant over j)
#pragma unroll
    for (int nt = 0; nt < 4; ++nt)
        creg[nt] = cArr[64 * w + 16 * nt + m] + qa[(size_t)i * 256 + 64 * w + 16 * nt + m];

    // builder: wave w builds A-frag (sub s_, k-half h_) of relu1
    const int s_ = w >> 1, h_ = w & 1;
    const unsigned short* bsrc  = aJ + m * 64 + h_ * 32 + q * 8;
    const float*          ibase = aI + i * 64 + h_ * 32 + q * 8;
    float iv[8];
    *(float4*)(iv)     = *(const float4*)(ibase);
    *(float4*)(iv + 4) = *(const float4*)(ibase + 4);

    const float* vbase  = vPT + (size_t)(16 * w + m) * NPTS;
    const float* knbase = knat + (size_t)(64 * w + m) * NPTS;

    // ka registers: current tile (ka0/ka1) + prefetch set (kn0/kn1).
    f32x4 ka0[4], ka1[4], kn0[4], kn1[4];
#pragma unroll
    for (int nt = 0; nt < 4; ++nt) {
        ka0[nt] = *(const f32x4*)(knbase + (size_t)nt * 16 * NPTS + 4 * q);
        ka1[nt] = *(const f32x4*)(knbase + (size_t)nt * 16 * NPTS + 16 + 4 * q);
    }

    // prologue: build this wave's task for tile 0 into buffer 0
    {
        const sh8 raw = *(const sh8*)(bsrc + (size_t)(16 * s_) * 64);
        float t[8];
#pragma unroll
        for (int e = 0; e < 8; ++e)
            t[e] = fmaxf(iv[e] - b2f((unsigned short)raw[e]), 0.f);
        uint4 pk;
        pk.x = pk2(t[0], t[1]); pk.y = pk2(t[2], t[3]);
        pk.z = pk2(t[4], t[5]); pk.w = pk2(t[6], t[7]);
        AfL[0][s_][h_][lane] = pk;
    }
    __syncthreads();

    float num = 0.f, den = 0.f;
    const f32x4 z4 = {0.f, 0.f, 0.f, 0.f};
    f32x4 aRp0 = z4, aRp1 = z4;   // previous tile's G3 results (pipeline carry)

    for (int n = 0; n < 32; ++n) {
        const int pb = n & 1, nb = pb ^ 1;
        const int j0 = n << 5;

        // ---- TOP-OF-ITER issue block: everything consumed later ----
        // ka prefetch for tile n+1 (consumed NEXT iter; barrier drain at the
        // end of THIS iter has the whole body as cover) — the R17 fix.
        if (n < 31) {
#pragma unroll
            for (int nt = 0; nt < 4; ++nt) {
                kn0[nt] = *(const f32x4*)(knbase + (size_t)nt * 16 * NPTS + j0 + 32 + 4 * q);
                kn1[nt] = *(const f32x4*)(knbase + (size_t)nt * 16 * NPTS + j0 + 48 + 4 * q);
            }
        }
        // next tile's raw global load (this wave's single task)
        sh8 rawN;
        if (n < 31) rawN = *(const sh8*)(bsrc + (size_t)(j0 + 32 + 16 * s_) * 64);
        // v values for own tile (C-operand of G3)
        const float4 vj0 = *(const float4*)(vbase + j0 + 4 * q);
        const float4 vj1 = *(const float4*)(vbase + j0 + 16 + 4 * q);

        // ---- A-frags (relu1 only: 4 b128 reads) ----
        const sh8 A00 = *(const sh8*)&AfL[pb][0][0][lane];
        const sh8 A01 = *(const sh8*)&AfL[pb][0][1][lane];
        const sh8 A10 = *(const sh8*)&AfL[pb][1][0][lane];
        const sh8 A11 = *(const sh8*)&AfL[pb][1][1][lane];

        // ---- sub 0: G1 (K=64) + KNA add + H-write (fp8 pack) ----
        {
            f32x4 acc[4];
#pragma unroll
            for (int nt = 0; nt < 4; ++nt) {
                const f32x4 cv = {creg[nt], creg[nt], creg[nt], creg[nt]};
                acc[nt] = __builtin_amdgcn_mfma_f32_16x16x32_bf16(A00, Bf[0 * 4 + nt], cv, 0, 0, 0);
                acc[nt] = __builtin_amdgcn_mfma_f32_16x16x32_bf16(A01, Bf[1 * 4 + nt], acc[nt], 0, 0, 0);
                acc[nt] = acc[nt] + ka0[nt];
            }
            unsigned char* hw = Hs[pb][0] + (4 * q) * 272 + 64 * w + 4 * m;
#pragma unroll
            for (int r = 0; r < 4; ++r)
                *(unsigned*)(hw + r * 272) = pk4fp8(fmaxf(acc[0][r], 0.f), fmaxf(acc[1][r], 0.f),
                                                   fmaxf(acc[2][r], 0.f), fmaxf(acc[3][r], 0.f));
        }

        // ---- sub 1: G1 + KNA add + H-write ----
        {
            f32x4 acc[4];
#pragma unroll
            for (int nt = 0; nt < 4; ++nt) {
                const f32x4 cv = {creg[nt], creg[nt], creg[nt], creg[nt]};
                acc[nt] = __builtin_amdgcn_mfma_f32_16x16x32_bf16(A10, Bf[0 * 4 + nt], cv, 0, 0, 0);
                acc[nt] = __builtin_amdgcn_mfma_f32_16x16x32_bf16(A11, Bf[1 * 4 + nt], acc[nt], 0, 0, 0);
                acc[nt] = acc[nt] + ka1[nt];
            }
            unsigned char* hw = Hs[pb][1] + (4 * q) * 272 + 64 * w + 4 * m;
#pragma unroll
            for (int r = 0; r < 4; ++r)
                *(unsigned*)(hw + r * 272) = pk4fp8(fmaxf(acc[0][r], 0.f), fmaxf(acc[1][r], 0.f),
                                                   fmaxf(acc[2][r], 0.f), fmaxf(acc[3][r], 0.f));
        }

        // ---- deferred-G2 LDS loads for tile n-1 (Hs[nb], published last barrier) ----
        i32x8 h00, h01, h10, h11;
        if (n) {
            h00 = ld32B(Hs[nb][0] + m * 272 + 0   + 32 * q);
            h01 = ld32B(Hs[nb][0] + m * 272 + 128 + 32 * q);
            h10 = ld32B(Hs[nb][1] + m * 272 + 0   + 32 * q);
            h11 = ld32B(Hs[nb][1] + m * 272 + 128 + 32 * q);
        }

        // ---- deferred G2 for tile n-1: simL2 + softmax accumulation ----
        if (n) {
            f32x4 aS0 = z4, aS1 = z4;
            aS0 = __builtin_amdgcn_mfma_scale_f32_16x16x128_f8f6f4(
                h00, W2f[0], aS0, 0, 0, 0, 127, 0, 127);
            aS0 = __builtin_amdgcn_mfma_scale_f32_16x16x128_f8f6f4(
                h01, W2f[1], aS0, 0, 0, 0, 127, 0, 127);
            aS1 = __builtin_amdgcn_mfma_scale_f32_16x16x128_f8f6f4(
                h10, W2f[0], aS1, 0, 0, 0, 127, 0, 127);
            aS1 = __builtin_amdgcn_mfma_scale_f32_16x16x128_f8f6f4(
                h11, W2f[1], aS1, 0, 0, 0, 127, 0, 127);
#pragma unroll
            for (int r = 0; r < 4; ++r) {
                const float e0 = EXP2(aS0[r]);
                num = fmaf(e0, aRp0[r], num);
                den += e0;
                const float e1 = EXP2(aS1[r]);
                num = fmaf(e1, aRp1[r], num);
                den += e1;
            }
        }

        // ---- G3 (pre-barrier): rpe + v for tile n, aR carried to iter n+1 ----
        const f32x4 vc0 = {vj0.x, vj0.y, vj0.z, vj0.w};
        const f32x4 vc1 = {vj1.x, vj1.y, vj1.z, vj1.w};
        f32x4 aR0 = __builtin_amdgcn_mfma_f32_16x16x32_bf16(A00, P2f[0], vc0, 0, 0, 0);
        aR0 = __builtin_amdgcn_mfma_f32_16x16x32_bf16(A01, P2f[1], aR0, 0, 0, 0);
        f32x4 aR1 = __builtin_amdgcn_mfma_f32_16x16x32_bf16(A10, P2f[0], vc1, 0, 0, 0);
        aR1 = __builtin_amdgcn_mfma_f32_16x16x32_bf16(A11, P2f[1], aR1, 0, 0, 0);
        aRp0 = aR0;
        aRp1 = aR1;

        // build next tile's A-frag (this wave's single task)
        if (n < 31) {
            float t[8];
#pragma unroll
            for (int e = 0; e < 8; ++e)
                t[e] = fmaxf(iv[e] - b2f((unsigned short)rawN[e]), 0.f);
            uint4 pk;
            pk.x = pk2(t[0], t[1]); pk.y = pk2(t[2], t[3]);
            pk.z = pk2(t[4], t[5]); pk.w = pk2(t[6], t[7]);
            AfL[nb][s_][h_][lane] = pk;
        }

        __syncthreads();  // publishes Hs[pb][*]/AfL[nb][*]; drains kn loads (full-body cover)

        // ---- rotate ka buffers POST-barrier (values resident; pure v_movs) ----
        if (n < 31) {
#pragma unroll
            for (int nt = 0; nt < 4; ++nt) {
                ka0[nt] = kn0[nt];
                ka1[nt] = kn1[nt];
            }
        }
    }

    // ---- epilogue: deferred G2 for the final tile (pb=1, published above) ----
    {
        f32x4 aS0 = z4, aS1 = z4;
        const i32x8 h00 = ld32B(Hs[1][0] + m * 272 + 0   + 32 * q);
        const i32x8 h01 = ld32B(Hs[1][0] + m * 272 + 128 + 32 * q);
        const i32x8 h10 = ld32B(Hs[1][1] + m * 272 + 0   + 32 * q);
        const i32x8 h11 = ld32B(Hs[1][1] + m * 272 + 128 + 32 * q);
        aS0 = __builtin_amdgcn_mfma_scale_f32_16x16x128_f8f6f4(
            h00, W2f[0], aS0, 0, 0, 0, 127, 0, 127);
        aS0 = __builtin_amdgcn_mfma_scale_f32_16x16x128_f8f6f4(
            h01, W2f[1], aS0, 0, 0, 0, 127, 0, 127);
        aS1 = __builtin_amdgcn_mfma_scale_f32_16x16x128_f8f6f4(
            h10, W2f[0], aS1, 0, 0, 0, 127, 0, 127);
        aS1 = __builtin_amdgcn_mfma_scale_f32_16x16x128_f8f6f4(
            h11, W2f[1], aS1, 0, 0, 0, 127, 0, 127);
#pragma unroll
        for (int r = 0; r < 4; ++r) {
            const float e0 = EXP2(aS0[r]);
            num = fmaf(e0, aRp0[r], num);
            den += e0;
            const float e1 = EXP2(aS1[r]);
            num = fmaf(e1, aRp1[r], num);
            den += e1;
        }
    }

    // reduce the 4 quad-partials (lanes m, m+16, m+32, m+48)
    num += __shfl_xor(num, 16);
    num += __shfl_xor(num, 32);
    den += __shfl_xor(den, 16);
    den += __shfl_xor(den, 32);
    if (q == 0) out[i * 64 + 16 * w + m] = num / den;
}

extern "C" void kernel_launch(void* const* d_in, const int* in_sizes, int n_in,
                              void* d_out, int out_size, void* d_ws, size_t ws_size,
                              hipStream_t stream) {
    const float* x   = (const float*)d_in[0];
    const float* pos = (const float*)d_in[1];
    const float* Wq  = (const float*)d_in[2];
    const float* Wk  = (const float*)d_in[3];
    const float* Wv  = (const float*)d_in[4];
    const float* pW1 = (const float*)d_in[5];
    const float* pb1 = (const float*)d_in[6];
    const float* pW2 = (const float*)d_in[7];
    const float* pb2 = (const float*)d_in[8];
    const float* aW1 = (const float*)d_in[9];
    const float* ab1 = (const float*)d_in[10];
    const float* aW2 = (const float*)d_in[11];
    // d_in[12] = ab2: constant over j -> cancels in per-channel softmax, unused.

    char* ws = (char*)d_ws;
    unsigned short* bextf = (unsigned short*)(ws + BEXT_OFF);
    unsigned char*  aw2f8 = (unsigned char*)(ws + AW2F_OFF);
    unsigned short* pw2f  = (unsigned short*)(ws + PW2F_OFF);
    float*          cArr  = (float*)(ws + CARR_OFF);
    float*          aIa   = (float*)(ws + AI_OFF);
    unsigned short* aJa   = (unsigned short*)(ws + AJ_OFF);
    float*          vPTa  = (float*)(ws + VPT_OFF);
    float*          qaA   = (float*)(ws + QA_OFF);
    float*          knatA = (float*)(ws + KNAT_OFF);

    prep_all<<<1681, 256, 0, stream>>>(x, pos, Wq, Wk, Wv, pW1, pb1, pW2, pb2, aW1, ab1, aW2,
                                       bextf, aw2f8, pw2f, cArr, vPTa, aIa, aJa, qaA, knatA);
    ptl_main<<<NPTS, 256, 0, stream>>>(aIa, aJa, vPTa, bextf, aw2f8, pw2f, cArr, qaA, knatA,
                                       (float*)d_out);
}

// Round 8
// 180.687 us; speedup vs baseline: 1.3486x; 1.3486x over previous
//
#include <hip/hip_runtime.h>

// PointTransformerLayer fused kernel (MI355X / gfx950) — round 18
//
// Math (bf16 G1/G3 verified R2/R4 absmax 0.031; fp8 H/G2 verified R9 0.0625):
//   relu1 = relu(aI_i - a_j)            aI = pos@pW1 + pb1, a = pos@pW1
//   S1    = [relu1 | (q_i - k_j)] @ [[W_pa],[aW1]]   (K=128), W_pa = pW2@aW1
//   H     = relu(S1 + c), c = ab1 + pb2@aW1          (c folded into G1 C-op)
//   simL2 = H @ (aW2*log2e)              (ab2 softmax-invariant -> dropped)
//   rpe   = relu1 @ pW2 ; vv = (v+pb2)_j + rpe       (v folded into G3 C-op)
//   out_i[d] = sum_j 2^simL2 * vv / sum_j 2^simL2
//
// R18 = R14 EXACTLY (120.6us best: G2 software-pipelined, (256,2)) + T5
//   s_setprio(1) around the MFMA clusters (G1 sub0/sub1, G2, G3).
//   Evidence trail for the revert: R15/R16/R17 (knat decomposition with 3
//   mutually-exclusive ka schedules) all land 175-181us — the 8 extra
//   16-row-scatter L2 wave-loads/iter are un-hideable (schedule-invariant);
//   trading 16 MFMAs for an L2 stream loses.  Decision rule fired.
//   setprio regime check: 2 independent blocks/CU drift out of phase (no
//   inter-block sync) = the phase-diverse regime where T5 measured +4-7%;
//   R12's setprio was confounded by its occupancy-spill disaster.

typedef float f32x4 __attribute__((ext_vector_type(4)));
typedef int   i32x8 __attribute__((ext_vector_type(8)));
using sh8 = __attribute__((ext_vector_type(8))) short;  // 8 bf16 (4 VGPRs)

static constexpr int NPTS = 1024;

#if __has_builtin(__builtin_amdgcn_exp2f)
#define EXP2(x) __builtin_amdgcn_exp2f(x)
#else
#define EXP2(x) exp2f(x)
#endif

// ---- ws layout (bytes) — identical to R9/R10/R14 ----
static constexpr size_t BEXT_OFF = 0;        // 4*16*64*8 bf16  = 65536 B
static constexpr size_t AW2F_OFF = 65536;    // fp8 frags: 2*4*64*32 = 16384 B
static constexpr size_t PW2F_OFF = 98304;    // 2*4*64*8 bf16   = 8192 B
static constexpr size_t CARR_OFF = 106496;   // 256 f32         = 1024 B
static constexpr size_t AI_OFF   = 107520;   // 1024*64 f32 (+pb1)
static constexpr size_t QI_OFF   = 369664;   // 1024*64 f32
static constexpr size_t VPT_OFF  = 631808;   // 64*1024 f32 (v+pb2, transposed)
static constexpr size_t AJ_OFF   = 893952;   // 1024*64 bf16
static constexpr size_t KN_OFF   = 1025024;  // 1024*64 bf16 (negated k)

__device__ __forceinline__ unsigned short f2b_rne(float f) {
    unsigned u = __float_as_uint(f);
    u += 0x7fffu + ((u >> 16) & 1u);
    return (unsigned short)(u >> 16);
}
// trunc-pack two f32 into bf16x2 — single v_perm_b32
__device__ __forceinline__ unsigned pk2(float lo, float hi) {
    return __builtin_amdgcn_perm(__float_as_uint(hi), __float_as_uint(lo), 0x07060302);
}
__device__ __forceinline__ float b2f(unsigned short s) {
    return __uint_as_float(((unsigned)s) << 16);
}
__device__ __forceinline__ unsigned char f2fp8(float v) {
    return (unsigned char)(__builtin_amdgcn_cvt_pk_fp8_f32(v, 0.f, 0, false) & 0xff);
}
__device__ __forceinline__ unsigned pk4fp8(float a, float b, float c, float d) {
    int r = __builtin_amdgcn_cvt_pk_fp8_f32(a, b, 0, false);
    r = __builtin_amdgcn_cvt_pk_fp8_f32(c, d, r, true);
    return (unsigned)r;
}
__device__ __forceinline__ i32x8 ld32B(const void* p) {
    const uint4 a = ((const uint4*)p)[0];
    const uint4 b = ((const uint4*)p)[1];
    i32x8 r;
    r[0] = a.x; r[1] = a.y; r[2] = a.z; r[3] = a.w;
    r[4] = b.x; r[5] = b.y; r[6] = b.z; r[7] = b.w;
    return r;
}

// ---------------- combined prep: weights (blocks 0..208) + points (209..464) ----------------
__global__ void prep_all(const float* __restrict__ x, const float* __restrict__ pos,
                         const float* __restrict__ Wq, const float* __restrict__ Wk,
                         const float* __restrict__ Wv, const float* __restrict__ pW1,
                         const float* __restrict__ pb1, const float* __restrict__ pW2,
                         const float* __restrict__ pb2, const float* __restrict__ aW1,
                         const float* __restrict__ ab1, const float* __restrict__ aW2,
                         unsigned short* __restrict__ bextf, unsigned char* __restrict__ aw2f8,
                         unsigned short* __restrict__ pw2f, float* __restrict__ cArr,
                         float* __restrict__ qI, unsigned short* __restrict__ kN,
                         float* __restrict__ vPT, float* __restrict__ aI,
                         unsigned short* __restrict__ aJ)
{
    const int b = blockIdx.x;
    if (b < 209) {
        const int idx = b * 256 + threadIdx.x;
        if (idx < 32768) {
            // B_ext[k][t]: k<64 -> W_pa = pW2@aW1, else aW1   (R2-verified)
            const int k = idx >> 8, t = idx & 255;
            float val;
            if (k < 64) {
                float s = 0.f;
                for (int d = 0; d < 64; ++d) s = fmaf(pW2[k * 64 + d], aW1[d * 256 + t], s);
                val = s;
            } else {
                val = aW1[(k - 64) * 256 + t];
            }
            const int kc = k >> 5, kl = k & 31, qq = kl >> 3, e = kl & 7;
            const int ntg = t >> 4, tl = t & 15;
            bextf[(((size_t)(kc * 16 + ntg) * 64) + (qq * 16 + tl)) * 8 + e] = f2b_rne(val);
        } else if (idx < 49152) {
            // aW2*log2e fp8 frags for mfma_scale 16x16x128 (R9-verified)
            const int r = idx - 32768;
            const int e = r & 31, lane = (r >> 5) & 63, wsl = (r >> 11) & 3, kb = r >> 13;
            const int q = lane >> 4, dl = lane & 15;
            const int kp = kb * 128 + q * 32 + e;
            const int t = 64 * (kp >> 6) + 16 * (kp & 3) + ((kp >> 2) & 15);
            const int d = 16 * wsl + dl;
            aw2f8[r] = f2fp8(aW2[t * 64 + d] * 1.4426950408889634f);
        } else if (idx < 53248) {
            // pW2 frags (R2-verified)
            const int r = idx - 49152;
            const int k = r >> 6, d = r & 63;
            const int kc = k >> 5, kl = k & 31, qq = kl >> 3, e = kl & 7;
            const int nt = d >> 4, dl = d & 15;
            pw2f[(((size_t)(kc * 4 + nt) * 64) + (qq * 16 + dl)) * 8 + e] = f2b_rne(pW2[k * 64 + d]);
        } else if (idx < 53504) {
            const int t = idx - 53248;
            float s = ab1[t];
            for (int d = 0; d < 64; ++d) s = fmaf(pb2[d], aW1[d * 256 + t], s);
            cArr[t] = s;
        }
    } else {
        // per-point prep: 4 points per block
        const int t = threadIdx.x, sub = t >> 6, d = t & 63;
        const int i = (b - 209) * 4 + sub;
        __shared__ float xs[4][64];
        xs[sub][d] = x[i * 64 + d];
        __syncthreads();
        float q = 0.f, k = 0.f, v = 0.f;
        for (int e = 0; e < 64; ++e) {
            const float xe = xs[sub][e];
            q = fmaf(xe, Wq[e * 64 + d], q);
            k = fmaf(xe, Wk[e * 64 + d], k);
            v = fmaf(xe, Wv[e * 64 + d], v);
        }
        const float a = pos[i * 2] * pW1[d] + pos[i * 2 + 1] * pW1[64 + d];
        qI[i * 64 + d] = q;
        kN[i * 64 + d] = f2b_rne(-k);
        vPT[d * NPTS + i] = v + pb2[d];
        aI[i * 64 + d] = a + pb1[d];
        aJ[i * 64 + d] = f2b_rne(a);
    }
}

// ---------------- main fused kernel: one block per query i, j-tile 32 ----------------
__global__ __launch_bounds__(256, 2) void ptl_main(
    const float* __restrict__ aI, const float* __restrict__ qI,
    const unsigned short* __restrict__ aJ, const unsigned short* __restrict__ kN,
    const float* __restrict__ vPT,
    const unsigned short* __restrict__ bextf, const unsigned char* __restrict__ aw2f8,
    const unsigned short* __restrict__ pw2f, const float* __restrict__ cArr,
    float* __restrict__ out)
{
    const int i    = blockIdx.x;
    const int tid  = threadIdx.x;
    const int w    = tid >> 6;    // wave: t-slice [64w,64w+64) for G1, d-slice [16w,16w+16) for G2/G3
    const int lane = tid & 63;
    const int m    = lane & 15;
    const int q    = lane >> 4;

    // double-buffered LDS: [buf][sub]  (16 KB + 17 KB = 33 KB)
    __shared__ __align__(16) uint4 AfL[2][2][4][64];
    __shared__ __align__(16) unsigned char Hs[2][2][16 * 272];    // fp8 H, stride 272

    // constant B fragments
    sh8 Bf[16];  // G1: [kc 0..3][nt 0..3]
#pragma unroll
    for (int kc = 0; kc < 4; ++kc)
#pragma unroll
        for (int nt = 0; nt < 4; ++nt)
            Bf[kc * 4 + nt] = *(const sh8*)(bextf + ((size_t)((kc * 16 + 4 * w + nt) * 64 + lane)) * 8);
    i32x8 W2f[2];  // G2 fp8: [kb 0..1], d-slice w
#pragma unroll
    for (int kb = 0; kb < 2; ++kb)
        W2f[kb] = ld32B(aw2f8 + ((size_t)((kb * 4 + w) * 64 + lane)) * 32);
    sh8 P2f[2];  // G3: [kc 0..1], d-slice w
#pragma unroll
    for (int kc = 0; kc < 2; ++kc)
        P2f[kc] = *(const sh8*)(pw2f + ((size_t)((kc * 4 + w) * 64 + lane)) * 8);

    float creg[4];
#pragma unroll
    for (int nt = 0; nt < 4; ++nt) creg[nt] = cArr[64 * w + 16 * nt + m];

    // builder: wave w builds A-frag k-block w (w<2: relu1 halves, w>=2: q-k halves)
    const int  half   = w & 1;
    const bool isRelu = (w < 2);
    const unsigned short* bsrc  = (isRelu ? aJ : kN) + m * 64 + half * 32 + q * 8;
    const float*          ibase = (isRelu ? aI : qI) + i * 64 + half * 32 + q * 8;
    float iv[8];
    *(float4*)(iv)     = *(const float4*)(ibase);
    *(float4*)(iv + 4) = *(const float4*)(ibase + 4);

    // prologue: build both subs of tile 0 into buffer 0
#pragma unroll
    for (int s = 0; s < 2; ++s) {
        const sh8 raw = *(const sh8*)(bsrc + (size_t)(16 * s) * 64);
        float t[8];
#pragma unroll
        for (int e = 0; e < 8; ++e)
            t[e] = isRelu ? fmaxf(iv[e] - b2f((unsigned short)raw[e]), 0.f)
                          : iv[e] + b2f((unsigned short)raw[e]);
        uint4 pk;
        pk.x = pk2(t[0], t[1]); pk.y = pk2(t[2], t[3]);
        pk.z = pk2(t[4], t[5]); pk.w = pk2(t[6], t[7]);
        AfL[0][s][w][lane] = pk;
    }
    __syncthreads();

    float num = 0.f, den = 0.f;
    const f32x4 z4 = {0.f, 0.f, 0.f, 0.f};
    f32x4 aRp0 = z4, aRp1 = z4;   // previous tile's G3 results (pipeline carry)
    const float* vbase = vPT + (size_t)(16 * w + m) * NPTS;

    for (int n = 0; n < 32; ++n) {
        const int pb = n & 1, nb = pb ^ 1;
        const int j0 = n << 5;

        // next tile's raw global loads, issued early (hidden under G1)
        sh8 raw0, raw1;
        if (n < 31) {
            raw0 = *(const sh8*)(bsrc + (size_t)(j0 + 32) * 64);
            raw1 = *(const sh8*)(bsrc + (size_t)(j0 + 48) * 64);
        }
        // v values for own tile (C-operand of G3)
        const float4 vj0 = *(const float4*)(vbase + j0 + 4 * q);
        const float4 vj1 = *(const float4*)(vbase + j0 + 16 + 4 * q);

        // ---- sub 0: G1 + H-write (fp8 pack) ----
        const sh8 A00 = *(const sh8*)&AfL[pb][0][0][lane];  // relu1
        const sh8 A01 = *(const sh8*)&AfL[pb][0][1][lane];
        const sh8 A02 = *(const sh8*)&AfL[pb][0][2][lane];
        const sh8 A03 = *(const sh8*)&AfL[pb][0][3][lane];
        {
            f32x4 acc[4];
            __builtin_amdgcn_s_setprio(1);
#pragma unroll
            for (int nt = 0; nt < 4; ++nt) {
                const f32x4 cv = {creg[nt], creg[nt], creg[nt], creg[nt]};
                acc[nt] = __builtin_amdgcn_mfma_f32_16x16x32_bf16(A00, Bf[0 * 4 + nt], cv, 0, 0, 0);
                acc[nt] = __builtin_amdgcn_mfma_f32_16x16x32_bf16(A01, Bf[1 * 4 + nt], acc[nt], 0, 0, 0);
                acc[nt] = __builtin_amdgcn_mfma_f32_16x16x32_bf16(A02, Bf[2 * 4 + nt], acc[nt], 0, 0, 0);
                acc[nt] = __builtin_amdgcn_mfma_f32_16x16x32_bf16(A03, Bf[3 * 4 + nt], acc[nt], 0, 0, 0);
            }
            __builtin_amdgcn_s_setprio(0);
            unsigned char* hw = Hs[pb][0] + (4 * q) * 272 + 64 * w + 4 * m;
#pragma unroll
            for (int r = 0; r < 4; ++r)
                *(unsigned*)(hw + r * 272) = pk4fp8(fmaxf(acc[0][r], 0.f), fmaxf(acc[1][r], 0.f),
                                                   fmaxf(acc[2][r], 0.f), fmaxf(acc[3][r], 0.f));
        }

        // ---- deferred-G2 LDS loads for tile n-1 (Hs[nb], published last barrier);
        //      issued here so ~16 MFMAs of G1 sub1 hide the LDS latency ----
        i32x8 h00, h01, h10, h11;
        if (n) {
            h00 = ld32B(Hs[nb][0] + m * 272 + 0   + 32 * q);
            h01 = ld32B(Hs[nb][0] + m * 272 + 128 + 32 * q);
            h10 = ld32B(Hs[nb][1] + m * 272 + 0   + 32 * q);
            h11 = ld32B(Hs[nb][1] + m * 272 + 128 + 32 * q);
        }

        // ---- sub 1: G1 + H-write ----
        const sh8 A10 = *(const sh8*)&AfL[pb][1][0][lane];  // relu1
        const sh8 A11 = *(const sh8*)&AfL[pb][1][1][lane];
        const sh8 A12 = *(const sh8*)&AfL[pb][1][2][lane];
        const sh8 A13 = *(const sh8*)&AfL[pb][1][3][lane];
        {
            f32x4 acc[4];
            __builtin_amdgcn_s_setprio(1);
#pragma unroll
            for (int nt = 0; nt < 4; ++nt) {
                const f32x4 cv = {creg[nt], creg[nt], creg[nt], creg[nt]};
                acc[nt] = __builtin_amdgcn_mfma_f32_16x16x32_bf16(A10, Bf[0 * 4 + nt], cv, 0, 0, 0);
                acc[nt] = __builtin_amdgcn_mfma_f32_16x16x32_bf16(A11, Bf[1 * 4 + nt], acc[nt], 0, 0, 0);
                acc[nt] = __builtin_amdgcn_mfma_f32_16x16x32_bf16(A12, Bf[2 * 4 + nt], acc[nt], 0, 0, 0);
                acc[nt] = __builtin_amdgcn_mfma_f32_16x16x32_bf16(A13, Bf[3 * 4 + nt], acc[nt], 0, 0, 0);
            }
            __builtin_amdgcn_s_setprio(0);
            unsigned char* hw = Hs[pb][1] + (4 * q) * 272 + 64 * w + 4 * m;
#pragma unroll
            for (int r = 0; r < 4; ++r)
                *(unsigned*)(hw + r * 272) = pk4fp8(fmaxf(acc[0][r], 0.f), fmaxf(acc[1][r], 0.f),
                                                   fmaxf(acc[2][r], 0.f), fmaxf(acc[3][r], 0.f));
        }

        // ---- deferred G2 for tile n-1: simL2 + softmax accumulation ----
        if (n) {
            f32x4 aS0 = z4, aS1 = z4;
            __builtin_amdgcn_s_setprio(1);
            aS0 = __builtin_amdgcn_mfma_scale_f32_16x16x128_f8f6f4(
                h00, W2f[0], aS0, 0, 0, 0, 127, 0, 127);
            aS0 = __builtin_amdgcn_mfma_scale_f32_16x16x128_f8f6f4(
                h01, W2f[1], aS0, 0, 0, 0, 127, 0, 127);
            aS1 = __builtin_amdgcn_mfma_scale_f32_16x16x128_f8f6f4(
                h10, W2f[0], aS1, 0, 0, 0, 127, 0, 127);
            aS1 = __builtin_amdgcn_mfma_scale_f32_16x16x128_f8f6f4(
                h11, W2f[1], aS1, 0, 0, 0, 127, 0, 127);
            __builtin_amdgcn_s_setprio(0);
#pragma unroll
            for (int r = 0; r < 4; ++r) {
                const float e0 = EXP2(aS0[r]);
                num = fmaf(e0, aRp0[r], num);
                den += e0;
                const float e1 = EXP2(aS1[r]);
                num = fmaf(e1, aRp1[r], num);
                den += e1;
            }
        }

        // ---- G3 (pre-barrier): rpe + v for tile n, aR carried to iter n+1 ----
        const f32x4 vc0 = {vj0.x, vj0.y, vj0.z, vj0.w};
        const f32x4 vc1 = {vj1.x, vj1.y, vj1.z, vj1.w};
        __builtin_amdgcn_s_setprio(1);
        f32x4 aR0 = __builtin_amdgcn_mfma_f32_16x16x32_bf16(A00, P2f[0], vc0, 0, 0, 0);
        aR0 = __builtin_amdgcn_mfma_f32_16x16x32_bf16(A01, P2f[1], aR0, 0, 0, 0);
        f32x4 aR1 = __builtin_amdgcn_mfma_f32_16x16x32_bf16(A10, P2f[0], vc1, 0, 0, 0);
        aR1 = __builtin_amdgcn_mfma_f32_16x16x32_bf16(A11, P2f[1], aR1, 0, 0, 0);
        __builtin_amdgcn_s_setprio(0);
        aRp0 = aR0;
        aRp1 = aR1;

        // build next tile's A-frags (this wave's k-block, both subs)
        if (n < 31) {
#pragma unroll
            for (int s = 0; s < 2; ++s) {
                const sh8 raw = s ? raw1 : raw0;
                float t[8];
#pragma unroll
                for (int e = 0; e < 8; ++e)
                    t[e] = isRelu ? fmaxf(iv[e] - b2f((unsigned short)raw[e]), 0.f)
                                  : iv[e] + b2f((unsigned short)raw[e]);
                uint4 pk;
                pk.x = pk2(t[0], t[1]); pk.y = pk2(t[2], t[3]);
                pk.z = pk2(t[4], t[5]); pk.w = pk2(t[6], t[7]);
                AfL[nb][s][w][lane] = pk;
            }
        }

        __syncthreads();  // publishes Hs[pb][*] (G2 of tile n, next iter) and AfL[nb][*]
    }

    // ---- epilogue: deferred G2 for the final tile (buffer 1, published above) ----
    {
        f32x4 aS0 = z4, aS1 = z4;
        const i32x8 h00 = ld32B(Hs[1][0] + m * 272 + 0   + 32 * q);
        const i32x8 h01 = ld32B(Hs[1][0] + m * 272 + 128 + 32 * q);
        const i32x8 h10 = ld32B(Hs[1][1] + m * 272 + 0   + 32 * q);
        const i32x8 h11 = ld32B(Hs[1][1] + m * 272 + 128 + 32 * q);
        aS0 = __builtin_amdgcn_mfma_scale_f32_16x16x128_f8f6f4(
            h00, W2f[0], aS0, 0, 0, 0, 127, 0, 127);
        aS0 = __builtin_amdgcn_mfma_scale_f32_16x16x128_f8f6f4(
            h01, W2f[1], aS0, 0, 0, 0, 127, 0, 127);
        aS1 = __builtin_amdgcn_mfma_scale_f32_16x16x128_f8f6f4(
            h10, W2f[0], aS1, 0, 0, 0, 127, 0, 127);
        aS1 = __builtin_amdgcn_mfma_scale_f32_16x16x128_f8f6f4(
            h11, W2f[1], aS1, 0, 0, 0, 127, 0, 127);
#pragma unroll
        for (int r = 0; r < 4; ++r) {
            const float e0 = EXP2(aS0[r]);
            num = fmaf(e0, aRp0[r], num);
            den += e0;
            const float e1 = EXP2(aS1[r]);
            num = fmaf(e1, aRp1[r], num);
            den += e1;
        }
    }

    // reduce the 4 quad-partials (lanes m, m+16, m+32, m+48)
    num += __shfl_xor(num, 16);
    num += __shfl_xor(num, 32);
    den += __shfl_xor(den, 16);
    den += __shfl_xor(den, 32);
    if (q == 0) out[i * 64 + 16 * w + m] = num / den;
}

extern "C" void kernel_launch(void* const* d_in, const int* in_sizes, int n_in,
                              void* d_out, int out_size, void* d_ws, size_t ws_size,
                              hipStream_t stream) {
    const float* x   = (const float*)d_in[0];
    const float* pos = (const float*)d_in[1];
    const float* Wq  = (const float*)d_in[2];
    const float* Wk  = (const float*)d_in[3];
    const float* Wv  = (const float*)d_in[4];
    const float* pW1 = (const float*)d_in[5];
    const float* pb1 = (const float*)d_in[6];
    const float* pW2 = (const float*)d_in[7];
    const float* pb2 = (const float*)d_in[8];
    const float* aW1 = (const float*)d_in[9];
    const float* ab1 = (const float*)d_in[10];
    const float* aW2 = (const float*)d_in[11];
    // d_in[12] = ab2: constant over j -> cancels in per-channel softmax, unused.

    char* ws = (char*)d_ws;
    unsigned short* bextf = (unsigned short*)(ws + BEXT_OFF);
    unsigned char*  aw2f8 = (unsigned char*)(ws + AW2F_OFF);
    unsigned short* pw2f  = (unsigned short*)(ws + PW2F_OFF);
    float*          cArr  = (float*)(ws + CARR_OFF);
    float*          aIa   = (float*)(ws + AI_OFF);
    float*          qIa   = (float*)(ws + QI_OFF);
    float*          vPTa  = (float*)(ws + VPT_OFF);
    unsigned short* aJa   = (unsigned short*)(ws + AJ_OFF);
    unsigned short* kNa   = (unsigned short*)(ws + KN_OFF);

    prep_all<<<465, 256, 0, stream>>>(x, pos, Wq, Wk, Wv, pW1, pb1, pW2, pb2, aW1, ab1, aW2,
                                      bextf, aw2f8, pw2f, cArr, qIa, kNa, vPTa, aIa, aJa);
    ptl_main<<<NPTS, 256, 0, stream>>>(aIa, qIa, aJa, kNa, vPTa, bextf, aw2f8, pw2f, cArr,
                                       (float*)d_out);
}

// Round 9
// 180.168 us; speedup vs baseline: 1.3525x; 1.0029x over previous
//
#include <hip/hip_runtime.h>

// PointTransformerLayer fused kernel (MI355X / gfx950) — round 19
//
// Math (per query, identical to R14; fp8 H/G2 verified R9, absmax 0.0625):
//   relu1 = relu(aI_i - a_j)            aI = pos@pW1 + pb1, a = pos@pW1
//   S1    = [relu1 | (q_i - k_j)] @ [[W_pa],[aW1]]   (K=128), W_pa = pW2@aW1
//   H     = relu(S1 + c), c = ab1 + pb2@aW1          (c folded into G1 C-op)
//   simL2 = H @ (aW2*log2e)              (ab2 softmax-invariant -> dropped)
//   rpe   = relu1 @ pW2 ; vv = (v+pb2)_j + rpe       (v folded into G3 C-op)
//   out_i[d] = sum_j 2^simL2 * vv / sum_j 2^simL2
//
// R19 = R14 structure x TWO QUERIES PER BLOCK (i0=2b, i0+1):
//   Evidence: R12-R18 established (a) register wall forbids >2 blocks/CU,
//   (b) source-level schedule motion is erased by the compiler, (c) extra
//   per-iter L2 streams are un-hideable, (d) per-iter time ~4600cy vs
//   ~2000cy identified work = chain-stall dominated at 2 waves/SIMD.
//   The remaining lever is per-wave ILP: 2 queries give every serial chain
//   (G1 4-deep, G2 scale, exp2) an independent twin, share ALL j-stream
//   loads (raw, vj) and ALL weight registers (Bf/W2f/P2f/creg), halve
//   barriers per query, and make the 512-block grid exactly one resident
//   round.  LDS 67.6KB (2 blocks/CU kept).  setprio removed (R18: neutral).
//   Spill tripwire: WRITE_SIZE must stay ~256KB.

typedef float f32x4 __attribute__((ext_vector_type(4)));
typedef int   i32x8 __attribute__((ext_vector_type(8)));
using sh8 = __attribute__((ext_vector_type(8))) short;  // 8 bf16 (4 VGPRs)

static constexpr int NPTS = 1024;

#if __has_builtin(__builtin_amdgcn_exp2f)
#define EXP2(x) __builtin_amdgcn_exp2f(x)
#else
#define EXP2(x) exp2f(x)
#endif

// ---- ws layout (bytes) — identical to R9/R10/R14 ----
static constexpr size_t BEXT_OFF = 0;        // 4*16*64*8 bf16  = 65536 B
static constexpr size_t AW2F_OFF = 65536;    // fp8 frags: 2*4*64*32 = 16384 B
static constexpr size_t PW2F_OFF = 98304;    // 2*4*64*8 bf16   = 8192 B
static constexpr size_t CARR_OFF = 106496;   // 256 f32         = 1024 B
static constexpr size_t AI_OFF   = 107520;   // 1024*64 f32 (+pb1)
static constexpr size_t QI_OFF   = 369664;   // 1024*64 f32
static constexpr size_t VPT_OFF  = 631808;   // 64*1024 f32 (v+pb2, transposed)
static constexpr size_t AJ_OFF   = 893952;   // 1024*64 bf16
static constexpr size_t KN_OFF   = 1025024;  // 1024*64 bf16 (negated k)

__device__ __forceinline__ unsigned short f2b_rne(float f) {
    unsigned u = __float_as_uint(f);
    u += 0x7fffu + ((u >> 16) & 1u);
    return (unsigned short)(u >> 16);
}
// trunc-pack two f32 into bf16x2 — single v_perm_b32
__device__ __forceinline__ unsigned pk2(float lo, float hi) {
    return __builtin_amdgcn_perm(__float_as_uint(hi), __float_as_uint(lo), 0x07060302);
}
__device__ __forceinline__ float b2f(unsigned short s) {
    return __uint_as_float(((unsigned)s) << 16);
}
__device__ __forceinline__ unsigned char f2fp8(float v) {
    return (unsigned char)(__builtin_amdgcn_cvt_pk_fp8_f32(v, 0.f, 0, false) & 0xff);
}
__device__ __forceinline__ unsigned pk4fp8(float a, float b, float c, float d) {
    int r = __builtin_amdgcn_cvt_pk_fp8_f32(a, b, 0, false);
    r = __builtin_amdgcn_cvt_pk_fp8_f32(c, d, r, true);
    return (unsigned)r;
}
__device__ __forceinline__ i32x8 ld32B(const void* p) {
    const uint4 a = ((const uint4*)p)[0];
    const uint4 b = ((const uint4*)p)[1];
    i32x8 r;
    r[0] = a.x; r[1] = a.y; r[2] = a.z; r[3] = a.w;
    r[4] = b.x; r[5] = b.y; r[6] = b.z; r[7] = b.w;
    return r;
}

// ---------------- combined prep: weights (blocks 0..208) + points (209..464) ----------------
__global__ void prep_all(const float* __restrict__ x, const float* __restrict__ pos,
                         const float* __restrict__ Wq, const float* __restrict__ Wk,
                         const float* __restrict__ Wv, const float* __restrict__ pW1,
                         const float* __restrict__ pb1, const float* __restrict__ pW2,
                         const float* __restrict__ pb2, const float* __restrict__ aW1,
                         const float* __restrict__ ab1, const float* __restrict__ aW2,
                         unsigned short* __restrict__ bextf, unsigned char* __restrict__ aw2f8,
                         unsigned short* __restrict__ pw2f, float* __restrict__ cArr,
                         float* __restrict__ qI, unsigned short* __restrict__ kN,
                         float* __restrict__ vPT, float* __restrict__ aI,
                         unsigned short* __restrict__ aJ)
{
    const int b = blockIdx.x;
    if (b < 209) {
        const int idx = b * 256 + threadIdx.x;
        if (idx < 32768) {
            // B_ext[k][t]: k<64 -> W_pa = pW2@aW1, else aW1   (R2-verified)
            const int k = idx >> 8, t = idx & 255;
            float val;
            if (k < 64) {
                float s = 0.f;
                for (int d = 0; d < 64; ++d) s = fmaf(pW2[k * 64 + d], aW1[d * 256 + t], s);
                val = s;
            } else {
                val = aW1[(k - 64) * 256 + t];
            }
            const int kc = k >> 5, kl = k & 31, qq = kl >> 3, e = kl & 7;
            const int ntg = t >> 4, tl = t & 15;
            bextf[(((size_t)(kc * 16 + ntg) * 64) + (qq * 16 + tl)) * 8 + e] = f2b_rne(val);
        } else if (idx < 49152) {
            // aW2*log2e fp8 frags for mfma_scale 16x16x128 (R9-verified)
            const int r = idx - 32768;
            const int e = r & 31, lane = (r >> 5) & 63, wsl = (r >> 11) & 3, kb = r >> 13;
            const int q = lane >> 4, dl = lane & 15;
            const int kp = kb * 128 + q * 32 + e;
            const int t = 64 * (kp >> 6) + 16 * (kp & 3) + ((kp >> 2) & 15);
            const int d = 16 * wsl + dl;
            aw2f8[r] = f2fp8(aW2[t * 64 + d] * 1.4426950408889634f);
        } else if (idx < 53248) {
            // pW2 frags (R2-verified)
            const int r = idx - 49152;
            const int k = r >> 6, d = r & 63;
            const int kc = k >> 5, kl = k & 31, qq = kl >> 3, e = kl & 7;
            const int nt = d >> 4, dl = d & 15;
            pw2f[(((size_t)(kc * 4 + nt) * 64) + (qq * 16 + dl)) * 8 + e] = f2b_rne(pW2[k * 64 + d]);
        } else if (idx < 53504) {
            const int t = idx - 53248;
            float s = ab1[t];
            for (int d = 0; d < 64; ++d) s = fmaf(pb2[d], aW1[d * 256 + t], s);
            cArr[t] = s;
        }
    } else {
        // per-point prep: 4 points per block
        const int t = threadIdx.x, sub = t >> 6, d = t & 63;
        const int i = (b - 209) * 4 + sub;
        __shared__ float xs[4][64];
        xs[sub][d] = x[i * 64 + d];
        __syncthreads();
        float q = 0.f, k = 0.f, v = 0.f;
        for (int e = 0; e < 64; ++e) {
            const float xe = xs[sub][e];
            q = fmaf(xe, Wq[e * 64 + d], q);
            k = fmaf(xe, Wk[e * 64 + d], k);
            v = fmaf(xe, Wv[e * 64 + d], v);
        }
        const float a = pos[i * 2] * pW1[d] + pos[i * 2 + 1] * pW1[64 + d];
        qI[i * 64 + d] = q;
        kN[i * 64 + d] = f2b_rne(-k);
        vPT[d * NPTS + i] = v + pb2[d];
        aI[i * 64 + d] = a + pb1[d];
        aJ[i * 64 + d] = f2b_rne(a);
    }
}

// ---------------- main fused kernel: one block per 2 queries, j-tile 32 ----------------
__global__ __launch_bounds__(256, 2) void ptl_main(
    const float* __restrict__ aI, const float* __restrict__ qI,
    const unsigned short* __restrict__ aJ, const unsigned short* __restrict__ kN,
    const float* __restrict__ vPT,
    const unsigned short* __restrict__ bextf, const unsigned char* __restrict__ aw2f8,
    const unsigned short* __restrict__ pw2f, const float* __restrict__ cArr,
    float* __restrict__ out)
{
    const int i0   = blockIdx.x * 2;
    const int tid  = threadIdx.x;
    const int w    = tid >> 6;    // wave: t-slice [64w,64w+64) for G1, d-slice [16w,16w+16) for G2/G3
    const int lane = tid & 63;
    const int m    = lane & 15;
    const int q    = lane >> 4;

    // double-buffered LDS, both queries: AfL 32 KB + Hs 34 KB = 67.6 KB
    __shared__ __align__(16) uint4 AfL[2][2][2][4][64];            // [buf][qry][sub][kc][lane]
    __shared__ __align__(16) unsigned char Hs[2][2][2][16 * 272];  // [buf][qry][sub], stride 272

    // constant B fragments — SHARED across both queries
    sh8 Bf[16];  // G1: [kc 0..3][nt 0..3]
#pragma unroll
    for (int kc = 0; kc < 4; ++kc)
#pragma unroll
        for (int nt = 0; nt < 4; ++nt)
            Bf[kc * 4 + nt] = *(const sh8*)(bextf + ((size_t)((kc * 16 + 4 * w + nt) * 64 + lane)) * 8);
    i32x8 W2f[2];  // G2 fp8: [kb 0..1], d-slice w
#pragma unroll
    for (int kb = 0; kb < 2; ++kb)
        W2f[kb] = ld32B(aw2f8 + ((size_t)((kb * 4 + w) * 64 + lane)) * 32);
    sh8 P2f[2];  // G3: [kc 0..1], d-slice w
#pragma unroll
    for (int kc = 0; kc < 2; ++kc)
        P2f[kc] = *(const sh8*)(pw2f + ((size_t)((kc * 4 + w) * 64 + lane)) * 8);

    float creg[4];  // c only — i-independent, shared
#pragma unroll
    for (int nt = 0; nt < 4; ++nt) creg[nt] = cArr[64 * w + 16 * nt + m];

    // builder: wave w builds A-frag k-block w for BOTH queries
    const int  half   = w & 1;
    const bool isRelu = (w < 2);
    const unsigned short* bsrc = (isRelu ? aJ : kN) + m * 64 + half * 32 + q * 8;  // j-only, shared
    const float* ib0 = (isRelu ? aI : qI) + (size_t)i0 * 64 + half * 32 + q * 8;
    const float* ib1 = ib0 + 64;
    float iv0[8], iv1[8];
    *(float4*)(iv0)     = *(const float4*)(ib0);
    *(float4*)(iv0 + 4) = *(const float4*)(ib0 + 4);
    *(float4*)(iv1)     = *(const float4*)(ib1);
    *(float4*)(iv1 + 4) = *(const float4*)(ib1 + 4);

    // builder for one sub (both queries) from a shared raw j-vector
    auto build2 = [&](int buf, int s, const sh8& raw) {
        float t0[8], t1[8];
#pragma unroll
        for (int e = 0; e < 8; ++e) {
            const float bj = b2f((unsigned short)raw[e]);
            t0[e] = isRelu ? fmaxf(iv0[e] - bj, 0.f) : iv0[e] + bj;
            t1[e] = isRelu ? fmaxf(iv1[e] - bj, 0.f) : iv1[e] + bj;
        }
        uint4 p0, p1;
        p0.x = pk2(t0[0], t0[1]); p0.y = pk2(t0[2], t0[3]);
        p0.z = pk2(t0[4], t0[5]); p0.w = pk2(t0[6], t0[7]);
        p1.x = pk2(t1[0], t1[1]); p1.y = pk2(t1[2], t1[3]);
        p1.z = pk2(t1[4], t1[5]); p1.w = pk2(t1[6], t1[7]);
        AfL[buf][0][s][w][lane] = p0;
        AfL[buf][1][s][w][lane] = p1;
    };

    // G1 (both subs) + G3 for one query; A-frags die at return, aR carried out
    auto g1g3 = [&](int buf, int qq, const f32x4& vc0, const f32x4& vc1,
                    f32x4& aRn0, f32x4& aRn1) {
        const sh8 A00 = *(const sh8*)&AfL[buf][qq][0][0][lane];
        const sh8 A01 = *(const sh8*)&AfL[buf][qq][0][1][lane];
        const sh8 A02 = *(const sh8*)&AfL[buf][qq][0][2][lane];
        const sh8 A03 = *(const sh8*)&AfL[buf][qq][0][3][lane];
        {
            f32x4 acc[4];
#pragma unroll
            for (int nt = 0; nt < 4; ++nt) {
                const f32x4 cv = {creg[nt], creg[nt], creg[nt], creg[nt]};
                acc[nt] = __builtin_amdgcn_mfma_f32_16x16x32_bf16(A00, Bf[0 * 4 + nt], cv, 0, 0, 0);
                acc[nt] = __builtin_amdgcn_mfma_f32_16x16x32_bf16(A01, Bf[1 * 4 + nt], acc[nt], 0, 0, 0);
                acc[nt] = __builtin_amdgcn_mfma_f32_16x16x32_bf16(A02, Bf[2 * 4 + nt], acc[nt], 0, 0, 0);
                acc[nt] = __builtin_amdgcn_mfma_f32_16x16x32_bf16(A03, Bf[3 * 4 + nt], acc[nt], 0, 0, 0);
            }
            unsigned char* hw = Hs[buf][qq][0] + (4 * q) * 272 + 64 * w + 4 * m;
#pragma unroll
            for (int r = 0; r < 4; ++r)
                *(unsigned*)(hw + r * 272) = pk4fp8(fmaxf(acc[0][r], 0.f), fmaxf(acc[1][r], 0.f),
                                                   fmaxf(acc[2][r], 0.f), fmaxf(acc[3][r], 0.f));
        }
        const sh8 A10 = *(const sh8*)&AfL[buf][qq][1][0][lane];
        const sh8 A11 = *(const sh8*)&AfL[buf][qq][1][1][lane];
        const sh8 A12 = *(const sh8*)&AfL[buf][qq][1][2][lane];
        const sh8 A13 = *(const sh8*)&AfL[buf][qq][1][3][lane];
        {
            f32x4 acc[4];
#pragma unroll
            for (int nt = 0; nt < 4; ++nt) {
                const f32x4 cv = {creg[nt], creg[nt], creg[nt], creg[nt]};
                acc[nt] = __builtin_amdgcn_mfma_f32_16x16x32_bf16(A10, Bf[0 * 4 + nt], cv, 0, 0, 0);
                acc[nt] = __builtin_amdgcn_mfma_f32_16x16x32_bf16(A11, Bf[1 * 4 + nt], acc[nt], 0, 0, 0);
                acc[nt] = __builtin_amdgcn_mfma_f32_16x16x32_bf16(A12, Bf[2 * 4 + nt], acc[nt], 0, 0, 0);
                acc[nt] = __builtin_amdgcn_mfma_f32_16x16x32_bf16(A13, Bf[3 * 4 + nt], acc[nt], 0, 0, 0);
            }
            unsigned char* hw = Hs[buf][qq][1] + (4 * q) * 272 + 64 * w + 4 * m;
#pragma unroll
            for (int r = 0; r < 4; ++r)
                *(unsigned*)(hw + r * 272) = pk4fp8(fmaxf(acc[0][r], 0.f), fmaxf(acc[1][r], 0.f),
                                                   fmaxf(acc[2][r], 0.f), fmaxf(acc[3][r], 0.f));
        }
        // G3: rpe + v (C-op vc shared across queries; A-frags this query's)
        aRn0 = __builtin_amdgcn_mfma_f32_16x16x32_bf16(A00, P2f[0], vc0, 0, 0, 0);
        aRn0 = __builtin_amdgcn_mfma_f32_16x16x32_bf16(A01, P2f[1], aRn0, 0, 0, 0);
        aRn1 = __builtin_amdgcn_mfma_f32_16x16x32_bf16(A10, P2f[0], vc1, 0, 0, 0);
        aRn1 = __builtin_amdgcn_mfma_f32_16x16x32_bf16(A11, P2f[1], aRn1, 0, 0, 0);
    };

    // deferred G2 + softmax accumulation for one query
    auto g2acc = [&](int buf, int qq, const f32x4& p0, const f32x4& p1,
                     float& nm, float& dn) {
        const f32x4 z4l = {0.f, 0.f, 0.f, 0.f};
        const i32x8 h00 = ld32B(Hs[buf][qq][0] + m * 272 + 0   + 32 * q);
        const i32x8 h01 = ld32B(Hs[buf][qq][0] + m * 272 + 128 + 32 * q);
        const i32x8 h10 = ld32B(Hs[buf][qq][1] + m * 272 + 0   + 32 * q);
        const i32x8 h11 = ld32B(Hs[buf][qq][1] + m * 272 + 128 + 32 * q);
        f32x4 aS0 = z4l, aS1 = z4l;
        aS0 = __builtin_amdgcn_mfma_scale_f32_16x16x128_f8f6f4(h00, W2f[0], aS0, 0, 0, 0, 127, 0, 127);
        aS0 = __builtin_amdgcn_mfma_scale_f32_16x16x128_f8f6f4(h01, W2f[1], aS0, 0, 0, 0, 127, 0, 127);
        aS1 = __builtin_amdgcn_mfma_scale_f32_16x16x128_f8f6f4(h10, W2f[0], aS1, 0, 0, 0, 127, 0, 127);
        aS1 = __builtin_amdgcn_mfma_scale_f32_16x16x128_f8f6f4(h11, W2f[1], aS1, 0, 0, 0, 127, 0, 127);
#pragma unroll
        for (int r = 0; r < 4; ++r) {
            const float e0 = EXP2(aS0[r]);
            nm = fmaf(e0, p0[r], nm);
            dn += e0;
            const float e1 = EXP2(aS1[r]);
            nm = fmaf(e1, p1[r], nm);
            dn += e1;
        }
    };

    // prologue: build tile 0 (both subs, both queries) into buffer 0
    {
        const sh8 rA = *(const sh8*)(bsrc);
        const sh8 rB = *(const sh8*)(bsrc + (size_t)16 * 64);
        build2(0, 0, rA);
        build2(0, 1, rB);
    }
    __syncthreads();

    float num0 = 0.f, den0 = 0.f, num1 = 0.f, den1 = 0.f;
    const f32x4 z4 = {0.f, 0.f, 0.f, 0.f};
    f32x4 aRp00 = z4, aRp01 = z4, aRp10 = z4, aRp11 = z4;  // [qry][subhalf] carries
    const float* vbase = vPT + (size_t)(16 * w + m) * NPTS;

    for (int n = 0; n < 32; ++n) {
        const int pb = n & 1, nb = pb ^ 1;
        const int j0 = n << 5;

        // shared j-stream loads, issued early
        sh8 raw0, raw1;
        if (n < 31) {
            raw0 = *(const sh8*)(bsrc + (size_t)(j0 + 32) * 64);
            raw1 = *(const sh8*)(bsrc + (size_t)(j0 + 48) * 64);
        }
        const float4 vj0 = *(const float4*)(vbase + j0 + 4 * q);
        const float4 vj1 = *(const float4*)(vbase + j0 + 16 + 4 * q);
        const f32x4 vc0 = {vj0.x, vj0.y, vj0.z, vj0.w};
        const f32x4 vc1 = {vj1.x, vj1.y, vj1.z, vj1.w};

        // G1 + G3 per query (A-frags die inside; aR carried out)
        f32x4 aRn00, aRn01, aRn10, aRn11;
        g1g3(pb, 0, vc0, vc1, aRn00, aRn01);
        g1g3(pb, 1, vc0, vc1, aRn10, aRn11);

        // deferred G2 for tile n-1, both queries
        if (n) {
            g2acc(nb, 0, aRp00, aRp01, num0, den0);
            g2acc(nb, 1, aRp10, aRp11, num1, den1);
        }
        aRp00 = aRn00; aRp01 = aRn01;
        aRp10 = aRn10; aRp11 = aRn11;

        // build next tile's A-frags (both queries) from shared raws
        if (n < 31) {
            build2(nb, 0, raw0);
            build2(nb, 1, raw1);
        }

        __syncthreads();  // publishes Hs[pb][*][*] (G2 next iter) and AfL[nb][*]
    }

    // epilogue: deferred G2 for the final tile (buffer 1)
    g2acc(1, 0, aRp00, aRp01, num0, den0);
    g2acc(1, 1, aRp10, aRp11, num1, den1);

    // reduce the 4 quad-partials (lanes m, m+16, m+32, m+48)
    num0 += __shfl_xor(num0, 16);
    num0 += __shfl_xor(num0, 32);
    den0 += __shfl_xor(den0, 16);
    den0 += __shfl_xor(den0, 32);
    num1 += __shfl_xor(num1, 16);
    num1 += __shfl_xor(num1, 32);
    den1 += __shfl_xor(den1, 16);
    den1 += __shfl_xor(den1, 32);
    if (q == 0) {
        out[(size_t)i0 * 64 + 16 * w + m]       = num0 / den0;
        out[(size_t)(i0 + 1) * 64 + 16 * w + m] = num1 / den1;
    }
}

extern "C" void kernel_launch(void* const* d_in, const int* in_sizes, int n_in,
                              void* d_out, int out_size, void* d_ws, size_t ws_size,
                              hipStream_t stream) {
    const float* x   = (const float*)d_in[0];
    const float* pos = (const float*)d_in[1];
    const float* Wq  = (const float*)d_in[2];
    const float* Wk  = (const float*)d_in[3];
    const float* Wv  = (const float*)d_in[4];
    const float* pW1 = (const float*)d_in[5];
    const float* pb1 = (const float*)d_in[6];
    const float* pW2 = (const float*)d_in[7];
    const float* pb2 = (const float*)d_in[8];
    const float* aW1 = (const float*)d_in[9];
    const float* ab1 = (const float*)d_in[10];
    const float* aW2 = (const float*)d_in[11];
    // d_in[12] = ab2: constant over j -> cancels in per-channel softmax, unused.

    char* ws = (char*)d_ws;
    unsigned short* bextf = (unsigned short*)(ws + BEXT_OFF);
    unsigned char*  aw2f8 = (unsigned char*)(ws + AW2F_OFF);
    unsigned short* pw2f  = (unsigned short*)(ws + PW2F_OFF);
    float*          cArr  = (float*)(ws + CARR_OFF);
    float*          aIa   = (float*)(ws + AI_OFF);
    float*          qIa   = (float*)(ws + QI_OFF);
    float*          vPTa  = (float*)(ws + VPT_OFF);
    unsigned short* aJa   = (unsigned short*)(ws + AJ_OFF);
    unsigned short* kNa   = (unsigned short*)(ws + KN_OFF);

    prep_all<<<465, 256, 0, stream>>>(x, pos, Wq, Wk, Wv, pW1, pb1, pW2, pb2, aW1, ab1, aW2,
                                      bextf, aw2f8, pw2f, cArr, qIa, kNa, vPTa, aIa, aJa);
    ptl_main<<<NPTS / 2, 256, 0, stream>>>(aIa, qIa, aJa, kNa, vPTa, bextf, aw2f8, pw2f, cArr,
                                           (float*)d_out);
}

// Round 10
// 175.078 us; speedup vs baseline: 1.3918x; 1.0291x over previous
//
#include <hip/hip_runtime.h>

// PointTransformerLayer fused kernel (MI355X / gfx950) — round 20
//
// Math:
//   relu1 = relu(aI_i - a_j)            aI = pos@pW1 + pb1, a = pos@pW1
//   S1    = relu1 @ W_pa  +  (-k_j)@aW1  +  (q_i@aW1 + c)
//     kc0,1 A-frags = relu1 (built);  kc2,3 A-frags = kN VERBATIM COPIES
//     (kN is bf16, negated, already in frag layout — zero VALU);
//     q_i@aW1 = QA table (f32, prep), folded into creg ONCE per block.
//   H     = relu(S1);  simL2 = H @ (aW2*log2e)   (ab2 softmax-invariant)
//   rpe   = relu1 @ pW2 ; vv = (v+pb2)_j + rpe   (v folded into G3 C-op)
//   out_i[d] = sum_j 2^simL2 * vv / sum_j 2^simL2
//
// R20 = R14 structure with the q-k BUILDER DELETED (hybrid decomposition):
//   R19 (2 queries/block: all device totals constant, ILP 2x) was a NULL ->
//   the kernel is THROUGHPUT-bound on total issued work (VALU 52 + MFMA 33
//   = 85% combined), not latency-bound.  Only lever: remove instructions.
//   Builder VALU/block-iter 192 -> 112; per-iter VMEM count UNCHANGED
//   (2 raw loads/wave, same as R14) — no new per-iter L2 stream (the
//   R15-R17 failure mode).  QA is a per-block constant fold (4 loads at
//   init).  q's contribution now f32 (more accurate than bf16(q-k)).
//   G1/G2/G3 MFMA counts, LDS, barriers: unchanged.  Spill tripwire:
//   WRITE_SIZE ~256KB.

typedef float f32x4 __attribute__((ext_vector_type(4)));
typedef int   i32x8 __attribute__((ext_vector_type(8)));
using sh8 = __attribute__((ext_vector_type(8))) short;  // 8 bf16 (4 VGPRs)

static constexpr int NPTS = 1024;

#if __has_builtin(__builtin_amdgcn_exp2f)
#define EXP2(x) __builtin_amdgcn_exp2f(x)
#else
#define EXP2(x) exp2f(x)
#endif

// ---- ws layout (bytes) ----
static constexpr size_t BEXT_OFF = 0;        // 4*16*64*8 bf16  = 65536 B
static constexpr size_t AW2F_OFF = 65536;    // fp8 frags: 2*4*64*32 = 16384 B
static constexpr size_t PW2F_OFF = 98304;    // 2*4*64*8 bf16   = 8192 B
static constexpr size_t CARR_OFF = 106496;   // 256 f32         = 1024 B
static constexpr size_t AI_OFF   = 107520;   // 1024*64 f32 (+pb1)      = 262144 B
static constexpr size_t VPT_OFF  = 369664;   // 64*1024 f32 (v+pb2, T)  = 262144 B
static constexpr size_t AJ_OFF   = 631808;   // 1024*64 bf16            = 131072 B
static constexpr size_t KN_OFF   = 762880;   // 1024*64 bf16 (negated k)= 131072 B
static constexpr size_t QA_OFF   = 893952;   // 1024*256 f32 (q@aW1)    = 1048576 B

__device__ __forceinline__ unsigned short f2b_rne(float f) {
    unsigned u = __float_as_uint(f);
    u += 0x7fffu + ((u >> 16) & 1u);
    return (unsigned short)(u >> 16);
}
// trunc-pack two f32 into bf16x2 — single v_perm_b32
__device__ __forceinline__ unsigned pk2(float lo, float hi) {
    return __builtin_amdgcn_perm(__float_as_uint(hi), __float_as_uint(lo), 0x07060302);
}
__device__ __forceinline__ float b2f(unsigned short s) {
    return __uint_as_float(((unsigned)s) << 16);
}
__device__ __forceinline__ unsigned char f2fp8(float v) {
    return (unsigned char)(__builtin_amdgcn_cvt_pk_fp8_f32(v, 0.f, 0, false) & 0xff);
}
__device__ __forceinline__ unsigned pk4fp8(float a, float b, float c, float d) {
    int r = __builtin_amdgcn_cvt_pk_fp8_f32(a, b, 0, false);
    r = __builtin_amdgcn_cvt_pk_fp8_f32(c, d, r, true);
    return (unsigned)r;
}
__device__ __forceinline__ i32x8 ld32B(const void* p) {
    const uint4 a = ((const uint4*)p)[0];
    const uint4 b = ((const uint4*)p)[1];
    i32x8 r;
    r[0] = a.x; r[1] = a.y; r[2] = a.z; r[3] = a.w;
    r[4] = b.x; r[5] = b.y; r[6] = b.z; r[7] = b.w;
    return r;
}

// ---------------- combined prep ----------------
// blocks: [0,209) weights | [209,465) points (4/blk) | [465,1489) QA (1 i/blk)
__global__ void prep_all(const float* __restrict__ x, const float* __restrict__ pos,
                         const float* __restrict__ Wq, const float* __restrict__ Wk,
                         const float* __restrict__ Wv, const float* __restrict__ pW1,
                         const float* __restrict__ pb1, const float* __restrict__ pW2,
                         const float* __restrict__ pb2, const float* __restrict__ aW1,
                         const float* __restrict__ ab1, const float* __restrict__ aW2,
                         unsigned short* __restrict__ bextf, unsigned char* __restrict__ aw2f8,
                         unsigned short* __restrict__ pw2f, float* __restrict__ cArr,
                         unsigned short* __restrict__ kN, float* __restrict__ vPT,
                         float* __restrict__ aI, unsigned short* __restrict__ aJ,
                         float* __restrict__ qa)
{
    __shared__ float s1[4][64];
    __shared__ float s2[4][64];
    const int b = blockIdx.x;
    if (b < 209) {
        const int idx = b * 256 + threadIdx.x;
        if (idx < 32768) {
            // B_ext[k][t]: k<64 -> W_pa = pW2@aW1, else aW1   (R2-verified)
            const int k = idx >> 8, t = idx & 255;
            float val;
            if (k < 64) {
                float s = 0.f;
                for (int d = 0; d < 64; ++d) s = fmaf(pW2[k * 64 + d], aW1[d * 256 + t], s);
                val = s;
            } else {
                val = aW1[(k - 64) * 256 + t];
            }
            const int kc = k >> 5, kl = k & 31, qq = kl >> 3, e = kl & 7;
            const int ntg = t >> 4, tl = t & 15;
            bextf[(((size_t)(kc * 16 + ntg) * 64) + (qq * 16 + tl)) * 8 + e] = f2b_rne(val);
        } else if (idx < 49152) {
            // aW2*log2e fp8 frags for mfma_scale 16x16x128 (R9-verified)
            const int r = idx - 32768;
            const int e = r & 31, lane = (r >> 5) & 63, wsl = (r >> 11) & 3, kb = r >> 13;
            const int q = lane >> 4, dl = lane & 15;
            const int kp = kb * 128 + q * 32 + e;
            const int t = 64 * (kp >> 6) + 16 * (kp & 3) + ((kp >> 2) & 15);
            const int d = 16 * wsl + dl;
            aw2f8[r] = f2fp8(aW2[t * 64 + d] * 1.4426950408889634f);
        } else if (idx < 53248) {
            // pW2 frags (R2-verified)
            const int r = idx - 49152;
            const int k = r >> 6, d = r & 63;
            const int kc = k >> 5, kl = k & 31, qq = kl >> 3, e = kl & 7;
            const int nt = d >> 4, dl = d & 15;
            pw2f[(((size_t)(kc * 4 + nt) * 64) + (qq * 16 + dl)) * 8 + e] = f2b_rne(pW2[k * 64 + d]);
        } else if (idx < 53504) {
            const int t = idx - 53248;
            float s = ab1[t];
            for (int d = 0; d < 64; ++d) s = fmaf(pb2[d], aW1[d * 256 + t], s);
            cArr[t] = s;
        }
    } else if (b < 465) {
        // per-point prep: k, v, aI, aJ — 4 points per block
        const int t = threadIdx.x, sub = t >> 6, d = t & 63;
        const int i = (b - 209) * 4 + sub;
        s1[sub][d] = x[i * 64 + d];
        __syncthreads();
        float k = 0.f, v = 0.f;
        for (int e = 0; e < 64; ++e) {
            const float xe = s1[sub][e];
            k = fmaf(xe, Wk[e * 64 + d], k);
            v = fmaf(xe, Wv[e * 64 + d], v);
        }
        const float a = pos[i * 2] * pW1[d] + pos[i * 2 + 1] * pW1[64 + d];
        kN[i * 64 + d] = f2b_rne(-k);
        vPT[d * NPTS + i] = v + pb2[d];
        aI[i * 64 + d] = a + pb1[d];
        aJ[i * 64 + d] = f2b_rne(a);
    } else {
        // QA[i][t] = (x_i@Wq)@aW1, f32 (per-block-constant fold in main)
        const int i = b - 465, t = threadIdx.x;
        if (t < 64) s1[0][t] = x[i * 64 + t];
        __syncthreads();
        if (t < 64) {
            float s = 0.f;
            for (int e = 0; e < 64; ++e) s = fmaf(s1[0][e], Wq[e * 64 + t], s);
            s2[0][t] = s;
        }
        __syncthreads();
        float s = 0.f;
        for (int d = 0; d < 64; ++d) s = fmaf(s2[0][d], aW1[d * 256 + t], s);
        qa[(size_t)i * 256 + t] = s;
    }
}

// ---------------- main fused kernel: one block per query i, j-tile 32 ----------------
__global__ __launch_bounds__(256, 2) void ptl_main(
    const float* __restrict__ aI, const unsigned short* __restrict__ aJ,
    const unsigned short* __restrict__ kN, const float* __restrict__ vPT,
    const unsigned short* __restrict__ bextf, const unsigned char* __restrict__ aw2f8,
    const unsigned short* __restrict__ pw2f, const float* __restrict__ cArr,
    const float* __restrict__ qa, float* __restrict__ out)
{
    const int i    = blockIdx.x;
    const int tid  = threadIdx.x;
    const int w    = tid >> 6;    // wave: t-slice [64w,64w+64) for G1, d-slice [16w,16w+16) for G2/G3
    const int lane = tid & 63;
    const int m    = lane & 15;
    const int q    = lane >> 4;

    // double-buffered LDS: [buf][sub][kc]  (16 KB + 17 KB = 33 KB)
    __shared__ __align__(16) uint4 AfL[2][2][4][64];
    __shared__ __align__(16) unsigned char Hs[2][2][16 * 272];    // fp8 H, stride 272

    // constant B fragments
    sh8 Bf[16];  // G1: [kc 0..3][nt 0..3]  (kc0,1 = W_pa; kc2,3 = aW1)
#pragma unroll
    for (int kc = 0; kc < 4; ++kc)
#pragma unroll
        for (int nt = 0; nt < 4; ++nt)
            Bf[kc * 4 + nt] = *(const sh8*)(bextf + ((size_t)((kc * 16 + 4 * w + nt) * 64 + lane)) * 8);
    i32x8 W2f[2];  // G2 fp8: [kb 0..1], d-slice w
#pragma unroll
    for (int kb = 0; kb < 2; ++kb)
        W2f[kb] = ld32B(aw2f8 + ((size_t)((kb * 4 + w) * 64 + lane)) * 32);
    sh8 P2f[2];  // G3: [kc 0..1], d-slice w
#pragma unroll
    for (int kc = 0; kc < 2; ++kc)
        P2f[kc] = *(const sh8*)(pw2f + ((size_t)((kc * 4 + w) * 64 + lane)) * 8);

    float creg[4];  // c + QA_i (both constant over j)
#pragma unroll
    for (int nt = 0; nt < 4; ++nt)
        creg[nt] = cArr[64 * w + 16 * nt + m] + qa[(size_t)i * 256 + 64 * w + 16 * nt + m];

    // builder task: wave w handles (sub s_, half h_): builds relu frag kc=h_
    // from aJ and COPIES kN verbatim into kc=2+h_ (zero VALU).
    const int s_ = w >> 1, h_ = w & 1;
    const unsigned short* bsrcA = aJ + m * 64 + h_ * 32 + q * 8;
    const unsigned short* bsrcK = kN + m * 64 + h_ * 32 + q * 8;
    const float*          ibase = aI + (size_t)i * 64 + h_ * 32 + q * 8;
    float iv[8];
    *(float4*)(iv)     = *(const float4*)(ibase);
    *(float4*)(iv + 4) = *(const float4*)(ibase + 4);

    // prologue: build tile 0 into buffer 0 (this wave's sub/half, kc h_ and 2+h_)
    {
        const sh8  rawA = *(const sh8*)(bsrcA + (size_t)(16 * s_) * 64);
        const uint4 rawK = *(const uint4*)(bsrcK + (size_t)(16 * s_) * 64);
        float t[8];
#pragma unroll
        for (int e = 0; e < 8; ++e)
            t[e] = fmaxf(iv[e] - b2f((unsigned short)rawA[e]), 0.f);
        uint4 pk;
        pk.x = pk2(t[0], t[1]); pk.y = pk2(t[2], t[3]);
        pk.z = pk2(t[4], t[5]); pk.w = pk2(t[6], t[7]);
        AfL[0][s_][h_][lane]     = pk;
        AfL[0][s_][2 + h_][lane] = rawK;
    }
    __syncthreads();

    float num = 0.f, den = 0.f;
    const f32x4 z4 = {0.f, 0.f, 0.f, 0.f};
    f32x4 aRp0 = z4, aRp1 = z4;   // previous tile's G3 results (pipeline carry)
    const float* vbase = vPT + (size_t)(16 * w + m) * NPTS;

    for (int n = 0; n < 32; ++n) {
        const int pb = n & 1, nb = pb ^ 1;
        const int j0 = n << 5;

        // next tile's raw global loads (this wave's sub/half), issued early
        sh8  rawA;
        uint4 rawK;
        if (n < 31) {
            rawA = *(const sh8*)(bsrcA + (size_t)(j0 + 32 + 16 * s_) * 64);
            rawK = *(const uint4*)(bsrcK + (size_t)(j0 + 32 + 16 * s_) * 64);
        }
        // v values for own tile (C-operand of G3)
        const float4 vj0 = *(const float4*)(vbase + j0 + 4 * q);
        const float4 vj1 = *(const float4*)(vbase + j0 + 16 + 4 * q);

        // ---- sub 0: G1 + H-write (fp8 pack) ----
        const sh8 A00 = *(const sh8*)&AfL[pb][0][0][lane];  // relu1 h0
        const sh8 A01 = *(const sh8*)&AfL[pb][0][1][lane];  // relu1 h1
        const sh8 A02 = *(const sh8*)&AfL[pb][0][2][lane];  // -k  h0
        const sh8 A03 = *(const sh8*)&AfL[pb][0][3][lane];  // -k  h1
        {
            f32x4 acc[4];
#pragma unroll
            for (int nt = 0; nt < 4; ++nt) {
                const f32x4 cv = {creg[nt], creg[nt], creg[nt], creg[nt]};
                acc[nt] = __builtin_amdgcn_mfma_f32_16x16x32_bf16(A00, Bf[0 * 4 + nt], cv, 0, 0, 0);
                acc[nt] = __builtin_amdgcn_mfma_f32_16x16x32_bf16(A01, Bf[1 * 4 + nt], acc[nt], 0, 0, 0);
                acc[nt] = __builtin_amdgcn_mfma_f32_16x16x32_bf16(A02, Bf[2 * 4 + nt], acc[nt], 0, 0, 0);
                acc[nt] = __builtin_amdgcn_mfma_f32_16x16x32_bf16(A03, Bf[3 * 4 + nt], acc[nt], 0, 0, 0);
            }
            unsigned char* hw = Hs[pb][0] + (4 * q) * 272 + 64 * w + 4 * m;
#pragma unroll
            for (int r = 0; r < 4; ++r)
                *(unsigned*)(hw + r * 272) = pk4fp8(fmaxf(acc[0][r], 0.f), fmaxf(acc[1][r], 0.f),
                                                   fmaxf(acc[2][r], 0.f), fmaxf(acc[3][r], 0.f));
        }

        // ---- deferred-G2 LDS loads for tile n-1 (Hs[nb], published last barrier) ----
        i32x8 h00, h01, h10, h11;
        if (n) {
            h00 = ld32B(Hs[nb][0] + m * 272 + 0   + 32 * q);
            h01 = ld32B(Hs[nb][0] + m * 272 + 128 + 32 * q);
            h10 = ld32B(Hs[nb][1] + m * 272 + 0   + 32 * q);
            h11 = ld32B(Hs[nb][1] + m * 272 + 128 + 32 * q);
        }

        // ---- sub 1: G1 + H-write ----
        const sh8 A10 = *(const sh8*)&AfL[pb][1][0][lane];
        const sh8 A11 = *(const sh8*)&AfL[pb][1][1][lane];
        const sh8 A12 = *(const sh8*)&AfL[pb][1][2][lane];
        const sh8 A13 = *(const sh8*)&AfL[pb][1][3][lane];
        {
            f32x4 acc[4];
#pragma unroll
            for (int nt = 0; nt < 4; ++nt) {
                const f32x4 cv = {creg[nt], creg[nt], creg[nt], creg[nt]};
                acc[nt] = __builtin_amdgcn_mfma_f32_16x16x32_bf16(A10, Bf[0 * 4 + nt], cv, 0, 0, 0);
                acc[nt] = __builtin_amdgcn_mfma_f32_16x16x32_bf16(A11, Bf[1 * 4 + nt], acc[nt], 0, 0, 0);
                acc[nt] = __builtin_amdgcn_mfma_f32_16x16x32_bf16(A12, Bf[2 * 4 + nt], acc[nt], 0, 0, 0);
                acc[nt] = __builtin_amdgcn_mfma_f32_16x16x32_bf16(A13, Bf[3 * 4 + nt], acc[nt], 0, 0, 0);
            }
            unsigned char* hw = Hs[pb][1] + (4 * q) * 272 + 64 * w + 4 * m;
#pragma unroll
            for (int r = 0; r < 4; ++r)
                *(unsigned*)(hw + r * 272) = pk4fp8(fmaxf(acc[0][r], 0.f), fmaxf(acc[1][r], 0.f),
                                                   fmaxf(acc[2][r], 0.f), fmaxf(acc[3][r], 0.f));
        }

        // ---- deferred G2 for tile n-1: simL2 + softmax accumulation ----
        if (n) {
            f32x4 aS0 = z4, aS1 = z4;
            aS0 = __builtin_amdgcn_mfma_scale_f32_16x16x128_f8f6f4(
                h00, W2f[0], aS0, 0, 0, 0, 127, 0, 127);
            aS0 = __builtin_amdgcn_mfma_scale_f32_16x16x128_f8f6f4(
                h01, W2f[1], aS0, 0, 0, 0, 127, 0, 127);
            aS1 = __builtin_amdgcn_mfma_scale_f32_16x16x128_f8f6f4(
                h10, W2f[0], aS1, 0, 0, 0, 127, 0, 127);
            aS1 = __builtin_amdgcn_mfma_scale_f32_16x16x128_f8f6f4(
                h11, W2f[1], aS1, 0, 0, 0, 127, 0, 127);
#pragma unroll
            for (int r = 0; r < 4; ++r) {
                const float e0 = EXP2(aS0[r]);
                num = fmaf(e0, aRp0[r], num);
                den += e0;
                const float e1 = EXP2(aS1[r]);
                num = fmaf(e1, aRp1[r], num);
                den += e1;
            }
        }

        // ---- G3 (pre-barrier): rpe + v for tile n, aR carried to iter n+1 ----
        const f32x4 vc0 = {vj0.x, vj0.y, vj0.z, vj0.w};
        const f32x4 vc1 = {vj1.x, vj1.y, vj1.z, vj1.w};
        f32x4 aR0 = __builtin_amdgcn_mfma_f32_16x16x32_bf16(A00, P2f[0], vc0, 0, 0, 0);
        aR0 = __builtin_amdgcn_mfma_f32_16x16x32_bf16(A01, P2f[1], aR0, 0, 0, 0);
        f32x4 aR1 = __builtin_amdgcn_mfma_f32_16x16x32_bf16(A10, P2f[0], vc1, 0, 0, 0);
        aR1 = __builtin_amdgcn_mfma_f32_16x16x32_bf16(A11, P2f[1], aR1, 0, 0, 0);
        aRp0 = aR0;
        aRp1 = aR1;

        // build next tile's A-frags: one relu frag (28 VALU) + one verbatim copy
        if (n < 31) {
            float t[8];
#pragma unroll
            for (int e = 0; e < 8; ++e)
                t[e] = fmaxf(iv[e] - b2f((unsigned short)rawA[e]), 0.f);
            uint4 pk;
            pk.x = pk2(t[0], t[1]); pk.y = pk2(t[2], t[3]);
            pk.z = pk2(t[4], t[5]); pk.w = pk2(t[6], t[7]);
            AfL[nb][s_][h_][lane]     = pk;
            AfL[nb][s_][2 + h_][lane] = rawK;
        }

        __syncthreads();  // publishes Hs[pb][*] (G2 next iter) and AfL[nb][*]
    }

    // ---- epilogue: deferred G2 for the final tile (buffer 1, published above) ----
    {
        f32x4 aS0 = z4, aS1 = z4;
        const i32x8 h00 = ld32B(Hs[1][0] + m * 272 + 0   + 32 * q);
        const i32x8 h01 = ld32B(Hs[1][0] + m * 272 + 128 + 32 * q);
        const i32x8 h10 = ld32B(Hs[1][1] + m * 272 + 0   + 32 * q);
        const i32x8 h11 = ld32B(Hs[1][1] + m * 272 + 128 + 32 * q);
        aS0 = __builtin_amdgcn_mfma_scale_f32_16x16x128_f8f6f4(
            h00, W2f[0], aS0, 0, 0, 0, 127, 0, 127);
        aS0 = __builtin_amdgcn_mfma_scale_f32_16x16x128_f8f6f4(
            h01, W2f[1], aS0, 0, 0, 0, 127, 0, 127);
        aS1 = __builtin_amdgcn_mfma_scale_f32_16x16x128_f8f6f4(
            h10, W2f[0], aS1, 0, 0, 0, 127, 0, 127);
        aS1 = __builtin_amdgcn_mfma_scale_f32_16x16x128_f8f6f4(
            h11, W2f[1], aS1, 0, 0, 0, 127, 0, 127);
#pragma unroll
        for (int r = 0; r < 4; ++r) {
            const float e0 = EXP2(aS0[r]);
            num = fmaf(e0, aRp0[r], num);
            den += e0;
            const float e1 = EXP2(aS1[r]);
            num = fmaf(e1, aRp1[r], num);
            den += e1;
        }
    }

    // reduce the 4 quad-partials (lanes m, m+16, m+32, m+48)
    num += __shfl_xor(num, 16);
    num += __shfl_xor(num, 32);
    den += __shfl_xor(den, 16);
    den += __shfl_xor(den, 32);
    if (q == 0) out[i * 64 + 16 * w + m] = num / den;
}

extern "C" void kernel_launch(void* const* d_in, const int* in_sizes, int n_in,
                              void* d_out, int out_size, void* d_ws, size_t ws_size,
                              hipStream_t stream) {
    const float* x   = (const float*)d_in[0];
    const float* pos = (const float*)d_in[1];
    const float* Wq  = (const float*)d_in[2];
    const float* Wk  = (const float*)d_in[3];
    const float* Wv  = (const float*)d_in[4];
    const float* pW1 = (const float*)d_in[5];
    const float* pb1 = (const float*)d_in[6];
    const float* pW2 = (const float*)d_in[7];
    const float* pb2 = (const float*)d_in[8];
    const float* aW1 = (const float*)d_in[9];
    const float* ab1 = (const float*)d_in[10];
    const float* aW2 = (const float*)d_in[11];
    // d_in[12] = ab2: constant over j -> cancels in per-channel softmax, unused.

    char* ws = (char*)d_ws;
    unsigned short* bextf = (unsigned short*)(ws + BEXT_OFF);
    unsigned char*  aw2f8 = (unsigned char*)(ws + AW2F_OFF);
    unsigned short* pw2f  = (unsigned short*)(ws + PW2F_OFF);
    float*          cArr  = (float*)(ws + CARR_OFF);
    float*          aIa   = (float*)(ws + AI_OFF);
    float*          vPTa  = (float*)(ws + VPT_OFF);
    unsigned short* aJa   = (unsigned short*)(ws + AJ_OFF);
    unsigned short* kNa   = (unsigned short*)(ws + KN_OFF);
    float*          qaA   = (float*)(ws + QA_OFF);

    prep_all<<<1489, 256, 0, stream>>>(x, pos, Wq, Wk, Wv, pW1, pb1, pW2, pb2, aW1, ab1, aW2,
                                       bextf, aw2f8, pw2f, cArr, kNa, vPTa, aIa, aJa, qaA);
    ptl_main<<<NPTS, 256, 0, stream>>>(aIa, aJa, kNa, vPTa, bextf, aw2f8, pw2f, cArr, qaA,
                                       (float*)d_out);
}

// Round 11
// 160.014 us; speedup vs baseline: 1.5229x; 1.0941x over previous
//
#include <hip/hip_runtime.h>

// PointTransformerLayer fused kernel (MI355X / gfx950) — round 21
//
// Math:
//   relu1 = relu(aI_i - a_j)            aI = pos@pW1 + pb1, a = pos@pW1
//   S1    = [relu1 | -k_j] @ [[W_pa],[aW1]] + (q_i@aW1 + c)   (K=128)
//     NEW: G1 in fp8 e4m3 via mfma_scale_f32_16x16x128 (unit scales) —
//     ONE MFMA per nt per sub instead of four 16x16x32 bf16.
//   H     = relu(S1);  simL2 = H @ (aW2*log2e)   (ab2 softmax-invariant)
//   rpe   = relu1 @ pW2 ; vv = (v+pb2)_j + rpe   (G3 stays bf16: relu1
//     kept in bf16 LDS frags for G3 — rpe accuracy unchanged)
//   out_i[d] = sum_j 2^simL2 * vv / sum_j 2^simL2
//
// R21 = R20 (112.6us) + G1 fp8: R20 proved the kernel ISSUE/THROUGHPUT-
//   bound (removing 80 VALU/blk-iter converted ~1:1 to wall time).  G1 is
//   32 of 40 MFMA/wave-iter (~75% of the 40us MFMA-pipe time); fp8 K=128
//   cuts it to 8 (pipe ~40.5 -> ~23us), frees 32 B-frag VGPRs, and keeps
//   per-iter VMEM count unchanged (no new L2 stream — the R15-R17 trap).
//   C/D layout of 16x16x128 == 16x16x32 (shape-determined) -> H-write,
//   G2 t-decode, softmax, G3 all byte-identical downstream.
//   Accuracy: S1 inputs bf16->fp8 adds ~3% to S1 before H's existing fp8
//   quantization; expect absmax 0.0625 -> ~0.07-0.09.  If FAILED: R22
//   reverts to R20 as final.  Spill tripwire: WRITE_SIZE ~256KB.

typedef float f32x4 __attribute__((ext_vector_type(4)));
typedef int   i32x8 __attribute__((ext_vector_type(8)));
using sh8 = __attribute__((ext_vector_type(8))) short;  // 8 bf16 (4 VGPRs)

static constexpr int NPTS = 1024;

#if __has_builtin(__builtin_amdgcn_exp2f)
#define EXP2(x) __builtin_amdgcn_exp2f(x)
#else
#define EXP2(x) exp2f(x)
#endif

// ---- ws layout (bytes) ----
static constexpr size_t BEXT8_OFF = 0;       // fp8 B_ext frags: 16*64*32 = 32768 B
static constexpr size_t AW2F_OFF = 32768;    // fp8 aW2 frags: 16384 B
static constexpr size_t PW2F_OFF = 49152;    // pW2 bf16 frags: 8192 B
static constexpr size_t CARR_OFF = 57344;    // 256 f32 = 1024 B
static constexpr size_t AI_OFF   = 58368;    // 1024*64 f32 (+pb1)      = 262144 B
static constexpr size_t VPT_OFF  = 320512;   // 64*1024 f32 (v+pb2, T)  = 262144 B
static constexpr size_t AJ_OFF   = 582656;   // 1024*64 bf16            = 131072 B
static constexpr size_t KN8_OFF  = 713728;   // 1024*64 fp8 (-k)        = 65536 B
static constexpr size_t QA_OFF   = 779264;   // 1024*256 f32 (q@aW1)    = 1048576 B

__device__ __forceinline__ unsigned short f2b_rne(float f) {
    unsigned u = __float_as_uint(f);
    u += 0x7fffu + ((u >> 16) & 1u);
    return (unsigned short)(u >> 16);
}
// trunc-pack two f32 into bf16x2 — single v_perm_b32
__device__ __forceinline__ unsigned pk2(float lo, float hi) {
    return __builtin_amdgcn_perm(__float_as_uint(hi), __float_as_uint(lo), 0x07060302);
}
__device__ __forceinline__ float b2f(unsigned short s) {
    return __uint_as_float(((unsigned)s) << 16);
}
__device__ __forceinline__ unsigned char f2fp8(float v) {
    return (unsigned char)(__builtin_amdgcn_cvt_pk_fp8_f32(v, 0.f, 0, false) & 0xff);
}
__device__ __forceinline__ unsigned pk4fp8(float a, float b, float c, float d) {
    int r = __builtin_amdgcn_cvt_pk_fp8_f32(a, b, 0, false);
    r = __builtin_amdgcn_cvt_pk_fp8_f32(c, d, r, true);
    return (unsigned)r;
}
__device__ __forceinline__ i32x8 ld32B(const void* p) {
    const uint4 a = ((const uint4*)p)[0];
    const uint4 b = ((const uint4*)p)[1];
    i32x8 r;
    r[0] = a.x; r[1] = a.y; r[2] = a.z; r[3] = a.w;
    r[4] = b.x; r[5] = b.y; r[6] = b.z; r[7] = b.w;
    return r;
}

// ---------------- combined prep ----------------
// blocks: [0,128) bext8 | [128,192) aw2f8 | [192,208) pw2f | 208 cArr
//         [209,465) points (4/blk) | [465,1489) QA (1 i/blk)
__global__ void prep_all(const float* __restrict__ x, const float* __restrict__ pos,
                         const float* __restrict__ Wq, const float* __restrict__ Wk,
                         const float* __restrict__ Wv, const float* __restrict__ pW1,
                         const float* __restrict__ pb1, const float* __restrict__ pW2,
                         const float* __restrict__ pb2, const float* __restrict__ aW1,
                         const float* __restrict__ ab1, const float* __restrict__ aW2,
                         unsigned char* __restrict__ bext8, unsigned char* __restrict__ aw2f8,
                         unsigned short* __restrict__ pw2f, float* __restrict__ cArr,
                         unsigned char* __restrict__ kN8, float* __restrict__ vPT,
                         float* __restrict__ aI, unsigned short* __restrict__ aJ,
                         float* __restrict__ qa)
{
    __shared__ float s1[4][64];
    __shared__ float s2[4][64];
    const int b = blockIdx.x;
    if (b < 128) {
        // fp8 B_ext frags for G1 mfma_scale 16x16x128.
        // frag(w,nt): lane = tl + 16*qq holds 32 bytes, k = 32*qq + e,
        // t = 64w + 16nt + tl.  B_ext[k][t] = k<64 ? W_pa[k][t] : aW1[k-64][t].
        const int r = b * 256 + threadIdx.x;  // < 32768
        const int frag = r >> 11, lane = (r >> 5) & 63, e = r & 31;
        const int w = frag >> 2, nt = frag & 3;
        const int tl = lane & 15, qq = lane >> 4;
        const int k = qq * 32 + e;
        const int t = 64 * w + 16 * nt + tl;
        float val;
        if (k < 64) {
            float s = 0.f;
            for (int d = 0; d < 64; ++d) s = fmaf(pW2[k * 64 + d], aW1[d * 256 + t], s);
            val = s;
        } else {
            val = aW1[(k - 64) * 256 + t];
        }
        bext8[r] = f2fp8(val);
    } else if (b < 192) {
        // aW2*log2e fp8 frags for G2 mfma_scale 16x16x128 (R9-verified)
        const int r = (b - 128) * 256 + threadIdx.x;  // < 16384
        const int e = r & 31, lane = (r >> 5) & 63, wsl = (r >> 11) & 3, kb = r >> 13;
        const int q = lane >> 4, dl = lane & 15;
        const int kp = kb * 128 + q * 32 + e;
        const int t = 64 * (kp >> 6) + 16 * (kp & 3) + ((kp >> 2) & 15);
        const int d = 16 * wsl + dl;
        aw2f8[r] = f2fp8(aW2[t * 64 + d] * 1.4426950408889634f);
    } else if (b < 208) {
        // pW2 bf16 frags for G3 (R2-verified)
        const int r = (b - 192) * 256 + threadIdx.x;  // < 4096
        const int k = r >> 6, d = r & 63;
        const int kc = k >> 5, kl = k & 31, qq = kl >> 3, e = kl & 7;
        const int nt = d >> 4, dl = d & 15;
        pw2f[(((size_t)(kc * 4 + nt) * 64) + (qq * 16 + dl)) * 8 + e] = f2b_rne(pW2[k * 64 + d]);
    } else if (b == 208) {
        const int t = threadIdx.x;
        float s = ab1[t];
        for (int d = 0; d < 64; ++d) s = fmaf(pb2[d], aW1[d * 256 + t], s);
        cArr[t] = s;
    } else if (b < 465) {
        // per-point prep: k(fp8), v, aI, aJ — 4 points per block
        const int t = threadIdx.x, sub = t >> 6, d = t & 63;
        const int i = (b - 209) * 4 + sub;
        s1[sub][d] = x[i * 64 + d];
        __syncthreads();
        float k = 0.f, v = 0.f;
        for (int e = 0; e < 64; ++e) {
            const float xe = s1[sub][e];
            k = fmaf(xe, Wk[e * 64 + d], k);
            v = fmaf(xe, Wv[e * 64 + d], v);
        }
        const float a = pos[i * 2] * pW1[d] + pos[i * 2 + 1] * pW1[64 + d];
        kN8[i * 64 + d] = f2fp8(-k);
        vPT[d * NPTS + i] = v + pb2[d];
        aI[i * 64 + d] = a + pb1[d];
        aJ[i * 64 + d] = f2b_rne(a);
    } else {
        // QA[i][t] = (x_i@Wq)@aW1, f32 (per-block-constant fold in main)
        const int i = b - 465, t = threadIdx.x;
        if (t < 64) s1[0][t] = x[i * 64 + t];
        __syncthreads();
        if (t < 64) {
            float s = 0.f;
            for (int e = 0; e < 64; ++e) s = fmaf(s1[0][e], Wq[e * 64 + t], s);
            s2[0][t] = s;
        }
        __syncthreads();
        float s = 0.f;
        for (int d = 0; d < 64; ++d) s = fmaf(s2[0][d], aW1[d * 256 + t], s);
        qa[(size_t)i * 256 + t] = s;
    }
}

// ---------------- main fused kernel: one block per query i, j-tile 32 ----------------
__global__ __launch_bounds__(256, 2) void ptl_main(
    const float* __restrict__ aI, const unsigned short* __restrict__ aJ,
    const unsigned char* __restrict__ kN8, const float* __restrict__ vPT,
    const unsigned char* __restrict__ bext8, const unsigned char* __restrict__ aw2f8,
    const unsigned short* __restrict__ pw2f, const float* __restrict__ cArr,
    const float* __restrict__ qa, float* __restrict__ out)
{
    const int i    = blockIdx.x;
    const int tid  = threadIdx.x;
    const int w    = tid >> 6;    // wave: t-slice [64w,64w+64) for G1, d-slice [16w,16w+16) for G2/G3
    const int lane = tid & 63;
    const int m    = lane & 15;
    const int q    = lane >> 4;

    // double-buffered LDS:
    //   AfL (bf16 relu1 frags, G3 only): [buf][sub][half][lane] = 8 KB
    //   Af8 (fp8 A-tile, G1): [buf][sub][16 rows x 144 stride]  = 9.2 KB
    //   Hs  (fp8 H, G2): stride 272                              = 17.4 KB
    __shared__ __align__(16) uint4 AfL[2][2][2][64];
    __shared__ __align__(16) unsigned char Af8[2][2][16 * 144];
    __shared__ __align__(16) unsigned char Hs[2][2][16 * 272];

    // constant B fragments
    i32x8 B8f[4];  // G1 fp8: [nt 0..3] for this wave's t-slice
#pragma unroll
    for (int nt = 0; nt < 4; ++nt)
        B8f[nt] = ld32B(bext8 + ((size_t)((4 * w + nt) * 64 + lane)) * 32);
    i32x8 W2f[2];  // G2 fp8: [kb 0..1], d-slice w
#pragma unroll
    for (int kb = 0; kb < 2; ++kb)
        W2f[kb] = ld32B(aw2f8 + ((size_t)((kb * 4 + w) * 64 + lane)) * 32);
    sh8 P2f[2];  // G3 bf16: [kc 0..1], d-slice w
#pragma unroll
    for (int kc = 0; kc < 2; ++kc)
        P2f[kc] = *(const sh8*)(pw2f + ((size_t)((kc * 4 + w) * 64 + lane)) * 8);

    float creg[4];  // c + QA_i (both constant over j)
#pragma unroll
    for (int nt = 0; nt < 4; ++nt)
        creg[nt] = cArr[64 * w + 16 * nt + m] + qa[(size_t)i * 256 + 64 * w + 16 * nt + m];

    // builder task: wave w = (sub s_, half h_).  Builds relu1 (bf16 for G3,
    // fp8 for G1) for k-chunk h_, and copies fp8 kN into kpos 64+32h_.
    const int s_ = w >> 1, h_ = w & 1;
    const unsigned short* bsrcA  = aJ  + m * 64 + h_ * 32 + q * 8;
    const unsigned char*  bsrcK8 = kN8 + m * 64 + h_ * 32 + q * 8;
    const float*          ibase  = aI + (size_t)i * 64 + h_ * 32 + q * 8;
    float iv[8];
    *(float4*)(iv)     = *(const float4*)(ibase);
    *(float4*)(iv + 4) = *(const float4*)(ibase + 4);

    // prologue: build tile 0 into buffer 0
    {
        const sh8  rawA  = *(const sh8*)(bsrcA + (size_t)(16 * s_) * 64);
        const uint2 rawK = *(const uint2*)(bsrcK8 + (size_t)(16 * s_) * 64);
        float t[8];
#pragma unroll
        for (int e = 0; e < 8; ++e)
            t[e] = fmaxf(iv[e] - b2f((unsigned short)rawA[e]), 0.f);
        uint4 pk;
        pk.x = pk2(t[0], t[1]); pk.y = pk2(t[2], t[3]);
        pk.z = pk2(t[4], t[5]); pk.w = pk2(t[6], t[7]);
        AfL[0][s_][h_][lane] = pk;
        uint2 f8;
        f8.x = pk4fp8(t[0], t[1], t[2], t[3]);
        f8.y = pk4fp8(t[4], t[5], t[6], t[7]);
        *(uint2*)(Af8[0][s_] + m * 144 + h_ * 32 + q * 8)      = f8;
        *(uint2*)(Af8[0][s_] + m * 144 + 64 + h_ * 32 + q * 8) = rawK;
    }
    __syncthreads();

    float num = 0.f, den = 0.f;
    const f32x4 z4 = {0.f, 0.f, 0.f, 0.f};
    f32x4 aRp0 = z4, aRp1 = z4;   // previous tile's G3 results (pipeline carry)
    const float* vbase = vPT + (size_t)(16 * w + m) * NPTS;

    for (int n = 0; n < 32; ++n) {
        const int pb = n & 1, nb = pb ^ 1;
        const int j0 = n << 5;

        // next tile's raw global loads (this wave's sub/half), issued early
        sh8  rawA;
        uint2 rawK;
        if (n < 31) {
            rawA = *(const sh8*)(bsrcA + (size_t)(j0 + 32 + 16 * s_) * 64);
            rawK = *(const uint2*)(bsrcK8 + (size_t)(j0 + 32 + 16 * s_) * 64);
        }
        // v values for own tile (C-operand of G3)
        const float4 vj0 = *(const float4*)(vbase + j0 + 4 * q);
        const float4 vj1 = *(const float4*)(vbase + j0 + 16 + 4 * q);

        // ---- sub 0: G1 fp8 K=128 (4 mfma_scale) + H-write ----
        {
            const i32x8 A8 = ld32B(Af8[pb][0] + m * 144 + 32 * q);
            f32x4 acc[4];
#pragma unroll
            for (int nt = 0; nt < 4; ++nt) {
                const f32x4 cv = {creg[nt], creg[nt], creg[nt], creg[nt]};
                acc[nt] = __builtin_amdgcn_mfma_scale_f32_16x16x128_f8f6f4(
                    A8, B8f[nt], cv, 0, 0, 0, 127, 0, 127);
            }
            unsigned char* hw = Hs[pb][0] + (4 * q) * 272 + 64 * w + 4 * m;
#pragma unroll
            for (int r = 0; r < 4; ++r)
                *(unsigned*)(hw + r * 272) = pk4fp8(fmaxf(acc[0][r], 0.f), fmaxf(acc[1][r], 0.f),
                                                   fmaxf(acc[2][r], 0.f), fmaxf(acc[3][r], 0.f));
        }

        // ---- deferred-G2 LDS loads for tile n-1 (Hs[nb], published last barrier) ----
        i32x8 h00, h01, h10, h11;
        if (n) {
            h00 = ld32B(Hs[nb][0] + m * 272 + 0   + 32 * q);
            h01 = ld32B(Hs[nb][0] + m * 272 + 128 + 32 * q);
            h10 = ld32B(Hs[nb][1] + m * 272 + 0   + 32 * q);
            h11 = ld32B(Hs[nb][1] + m * 272 + 128 + 32 * q);
        }

        // ---- sub 1: G1 fp8 + H-write ----
        {
            const i32x8 A8 = ld32B(Af8[pb][1] + m * 144 + 32 * q);
            f32x4 acc[4];
#pragma unroll
            for (int nt = 0; nt < 4; ++nt) {
                const f32x4 cv = {creg[nt], creg[nt], creg[nt], creg[nt]};
                acc[nt] = __builtin_amdgcn_mfma_scale_f32_16x16x128_f8f6f4(
                    A8, B8f[nt], cv, 0, 0, 0, 127, 0, 127);
            }
            unsigned char* hw = Hs[pb][1] + (4 * q) * 272 + 64 * w + 4 * m;
#pragma unroll
            for (int r = 0; r < 4; ++r)
                *(unsigned*)(hw + r * 272) = pk4fp8(fmaxf(acc[0][r], 0.f), fmaxf(acc[1][r], 0.f),
                                                   fmaxf(acc[2][r], 0.f), fmaxf(acc[3][r], 0.f));
        }

        // ---- G3 bf16 A-frag loads (AfL[pb]); latency hidden under G2 ----
        const sh8 A00 = *(const sh8*)&AfL[pb][0][0][lane];
        const sh8 A01 = *(const sh8*)&AfL[pb][0][1][lane];
        const sh8 A10 = *(const sh8*)&AfL[pb][1][0][lane];
        const sh8 A11 = *(const sh8*)&AfL[pb][1][1][lane];

        // ---- deferred G2 for tile n-1: simL2 + softmax accumulation ----
        if (n) {
            f32x4 aS0 = z4, aS1 = z4;
            aS0 = __builtin_amdgcn_mfma_scale_f32_16x16x128_f8f6f4(
                h00, W2f[0], aS0, 0, 0, 0, 127, 0, 127);
            aS0 = __builtin_amdgcn_mfma_scale_f32_16x16x128_f8f6f4(
                h01, W2f[1], aS0, 0, 0, 0, 127, 0, 127);
            aS1 = __builtin_amdgcn_mfma_scale_f32_16x16x128_f8f6f4(
                h10, W2f[0], aS1, 0, 0, 0, 127, 0, 127);
            aS1 = __builtin_amdgcn_mfma_scale_f32_16x16x128_f8f6f4(
                h11, W2f[1], aS1, 0, 0, 0, 127, 0, 127);
#pragma unroll
            for (int r = 0; r < 4; ++r) {
                const float e0 = EXP2(aS0[r]);
                num = fmaf(e0, aRp0[r], num);
                den += e0;
                const float e1 = EXP2(aS1[r]);
                num = fmaf(e1, aRp1[r], num);
                den += e1;
            }
        }

        // ---- G3 (pre-barrier, bf16): rpe + v for tile n, aR carried ----
        const f32x4 vc0 = {vj0.x, vj0.y, vj0.z, vj0.w};
        const f32x4 vc1 = {vj1.x, vj1.y, vj1.z, vj1.w};
        f32x4 aR0 = __builtin_amdgcn_mfma_f32_16x16x32_bf16(A00, P2f[0], vc0, 0, 0, 0);
        aR0 = __builtin_amdgcn_mfma_f32_16x16x32_bf16(A01, P2f[1], aR0, 0, 0, 0);
        f32x4 aR1 = __builtin_amdgcn_mfma_f32_16x16x32_bf16(A10, P2f[0], vc1, 0, 0, 0);
        aR1 = __builtin_amdgcn_mfma_f32_16x16x32_bf16(A11, P2f[1], aR1, 0, 0, 0);
        aRp0 = aR0;
        aRp1 = aR1;

        // build next tile's frags: relu1 (bf16+fp8) + fp8 kN copy
        if (n < 31) {
            float t[8];
#pragma unroll
            for (int e = 0; e < 8; ++e)
                t[e] = fmaxf(iv[e] - b2f((unsigned short)rawA[e]), 0.f);
            uint4 pk;
            pk.x = pk2(t[0], t[1]); pk.y = pk2(t[2], t[3]);
            pk.z = pk2(t[4], t[5]); pk.w = pk2(t[6], t[7]);
            AfL[nb][s_][h_][lane] = pk;
            uint2 f8;
            f8.x = pk4fp8(t[0], t[1], t[2], t[3]);
            f8.y = pk4fp8(t[4], t[5], t[6], t[7]);
            *(uint2*)(Af8[nb][s_] + m * 144 + h_ * 32 + q * 8)      = f8;
            *(uint2*)(Af8[nb][s_] + m * 144 + 64 + h_ * 32 + q * 8) = rawK;
        }

        __syncthreads();  // publishes Hs[pb][*] (G2 next iter), AfL/Af8[nb][*]
    }

    // ---- epilogue: deferred G2 for the final tile (buffer 1, published above) ----
    {
        f32x4 aS0 = z4, aS1 = z4;
        const i32x8 h00 = ld32B(Hs[1][0] + m * 272 + 0   + 32 * q);
        const i32x8 h01 = ld32B(Hs[1][0] + m * 272 + 128 + 32 * q);
        const i32x8 h10 = ld32B(Hs[1][1] + m * 272 + 0   + 32 * q);
        const i32x8 h11 = ld32B(Hs[1][1] + m * 272 + 128 + 32 * q);
        aS0 = __builtin_amdgcn_mfma_scale_f32_16x16x128_f8f6f4(
            h00, W2f[0], aS0, 0, 0, 0, 127, 0, 127);
        aS0 = __builtin_amdgcn_mfma_scale_f32_16x16x128_f8f6f4(
            h01, W2f[1], aS0, 0, 0, 0, 127, 0, 127);
        aS1 = __builtin_amdgcn_mfma_scale_f32_16x16x128_f8f6f4(
            h10, W2f[0], aS1, 0, 0, 0, 127, 0, 127);
        aS1 = __builtin_amdgcn_mfma_scale_f32_16x16x128_f8f6f4(
            h11, W2f[1], aS1, 0, 0, 0, 127, 0, 127);
#pragma unroll
        for (int r = 0; r < 4; ++r) {
            const float e0 = EXP2(aS0[r]);
            num = fmaf(e0, aRp0[r], num);
            den += e0;
            const float e1 = EXP2(aS1[r]);
            num = fmaf(e1, aRp1[r], num);
            den += e1;
        }
    }

    // reduce the 4 quad-partials (lanes m, m+16, m+32, m+48)
    num += __shfl_xor(num, 16);
    num += __shfl_xor(num, 32);
    den += __shfl_xor(den, 16);
    den += __shfl_xor(den, 32);
    if (q == 0) out[i * 64 + 16 * w + m] = num / den;
}

extern "C" void kernel_launch(void* const* d_in, const int* in_sizes, int n_in,
                              void* d_out, int out_size, void* d_ws, size_t ws_size,
                              hipStream_t stream) {
    const float* x   = (const float*)d_in[0];
    const float* pos = (const float*)d_in[1];
    const float* Wq  = (const float*)d_in[2];
    const float* Wk  = (const float*)d_in[3];
    const float* Wv  = (const float*)d_in[4];
    const float* pW1 = (const float*)d_in[5];
    const float* pb1 = (const float*)d_in[6];
    const float* pW2 = (const float*)d_in[7];
    const float* pb2 = (const float*)d_in[8];
    const float* aW1 = (const float*)d_in[9];
    const float* ab1 = (const float*)d_in[10];
    const float* aW2 = (const float*)d_in[11];
    // d_in[12] = ab2: constant over j -> cancels in per-channel softmax, unused.

    char* ws = (char*)d_ws;
    unsigned char*  bext8 = (unsigned char*)(ws + BEXT8_OFF);
    unsigned char*  aw2f8 = (unsigned char*)(ws + AW2F_OFF);
    unsigned short* pw2f  = (unsigned short*)(ws + PW2F_OFF);
    float*          cArr  = (float*)(ws + CARR_OFF);
    float*          aIa   = (float*)(ws + AI_OFF);
    float*          vPTa  = (float*)(ws + VPT_OFF);
    unsigned short* aJa   = (unsigned short*)(ws + AJ_OFF);
    unsigned char*  kN8a  = (unsigned char*)(ws + KN8_OFF);
    float*          qaA   = (float*)(ws + QA_OFF);

    prep_all<<<1489, 256, 0, stream>>>(x, pos, Wq, Wk, Wv, pW1, pb1, pW2, pb2, aW1, ab1, aW2,
                                       bext8, aw2f8, pw2f, cArr, kN8a, vPTa, aIa, aJa, qaA);
    ptl_main<<<NPTS, 256, 0, stream>>>(aIa, aJa, kN8a, vPTa, bext8, aw2f8, pw2f, cArr, qaA,
                                       (float*)d_out);
}

// Round 13
// 158.062 us; speedup vs baseline: 1.5417x; 1.0123x over previous
//
#include <hip/hip_runtime.h>

// PointTransformerLayer fused kernel (MI355X / gfx950) — round 23
// (= R22 resubmitted verbatim; R22's bench was an infra failure —
//  "container failed twice" — not a kernel verdict.)
//
// Math (identical to R21, absmax 0.06445312):
//   relu1 = relu(aI_i - a_j)            aI = pos@pW1 + pb1, a = pos@pW1
//   S1    = [relu1 | -k_j] @ [[W_pa],[aW1]] + (q_i@aW1 + c)   (K=128, fp8
//           e4m3 via mfma_scale_f32_16x16x128, unit scales)
//   H     = relu(S1);  simL2 = H @ (aW2*log2e)   (ab2 softmax-invariant)
//   rpe   = relu1 @ pW2 (bf16); vv = (v+pb2)_j + rpe
//   out_i[d] = sum_j 2^simL2 * vv / sum_j 2^simL2
//
// R23 = R21 EXACTLY (91.0us) except __launch_bounds__(256,2) -> (256,3).
//   Register-wall history: R13 forced 3/CU at ~190 live regs -> mild spill
//   (137us).  R21 freed ~30 permanent regs (B8f 32 vs Bf 64, A-transients
//   halved): est. peak ~165-170 = right at the 170-reg budget of 3
//   waves/SIMD.  LDS 34.8KB permits 4 blocks/CU (not binding).  Not
//   contradicted by R19's ILP-null: extra WAVES cover barrier drains and
//   pipe handoffs that intra-wave ILP cannot.
//   Pre-committed rule: WRITE_SIZE>1MB or dur>=91us -> revert to R21.

typedef float f32x4 __attribute__((ext_vector_type(4)));
typedef int   i32x8 __attribute__((ext_vector_type(8)));
using sh8 = __attribute__((ext_vector_type(8))) short;  // 8 bf16 (4 VGPRs)

static constexpr int NPTS = 1024;

#if __has_builtin(__builtin_amdgcn_exp2f)
#define EXP2(x) __builtin_amdgcn_exp2f(x)
#else
#define EXP2(x) exp2f(x)
#endif

// ---- ws layout (bytes) ----
static constexpr size_t BEXT8_OFF = 0;       // fp8 B_ext frags: 16*64*32 = 32768 B
static constexpr size_t AW2F_OFF = 32768;    // fp8 aW2 frags: 16384 B
static constexpr size_t PW2F_OFF = 49152;    // pW2 bf16 frags: 8192 B
static constexpr size_t CARR_OFF = 57344;    // 256 f32 = 1024 B
static constexpr size_t AI_OFF   = 58368;    // 1024*64 f32 (+pb1)      = 262144 B
static constexpr size_t VPT_OFF  = 320512;   // 64*1024 f32 (v+pb2, T)  = 262144 B
static constexpr size_t AJ_OFF   = 582656;   // 1024*64 bf16            = 131072 B
static constexpr size_t KN8_OFF  = 713728;   // 1024*64 fp8 (-k)        = 65536 B
static constexpr size_t QA_OFF   = 779264;   // 1024*256 f32 (q@aW1)    = 1048576 B

__device__ __forceinline__ unsigned short f2b_rne(float f) {
    unsigned u = __float_as_uint(f);
    u += 0x7fffu + ((u >> 16) & 1u);
    return (unsigned short)(u >> 16);
}
// trunc-pack two f32 into bf16x2 — single v_perm_b32
__device__ __forceinline__ unsigned pk2(float lo, float hi) {
    return __builtin_amdgcn_perm(__float_as_uint(hi), __float_as_uint(lo), 0x07060302);
}
__device__ __forceinline__ float b2f(unsigned short s) {
    return __uint_as_float(((unsigned)s) << 16);
}
__device__ __forceinline__ unsigned char f2fp8(float v) {
    return (unsigned char)(__builtin_amdgcn_cvt_pk_fp8_f32(v, 0.f, 0, false) & 0xff);
}
__device__ __forceinline__ unsigned pk4fp8(float a, float b, float c, float d) {
    int r = __builtin_amdgcn_cvt_pk_fp8_f32(a, b, 0, false);
    r = __builtin_amdgcn_cvt_pk_fp8_f32(c, d, r, true);
    return (unsigned)r;
}
__device__ __forceinline__ i32x8 ld32B(const void* p) {
    const uint4 a = ((const uint4*)p)[0];
    const uint4 b = ((const uint4*)p)[1];
    i32x8 r;
    r[0] = a.x; r[1] = a.y; r[2] = a.z; r[3] = a.w;
    r[4] = b.x; r[5] = b.y; r[6] = b.z; r[7] = b.w;
    return r;
}

// ---------------- combined prep ----------------
// blocks: [0,128) bext8 | [128,192) aw2f8 | [192,208) pw2f | 208 cArr
//         [209,465) points (4/blk) | [465,1489) QA (1 i/blk)
__global__ void prep_all(const float* __restrict__ x, const float* __restrict__ pos,
                         const float* __restrict__ Wq, const float* __restrict__ Wk,
                         const float* __restrict__ Wv, const float* __restrict__ pW1,
                         const float* __restrict__ pb1, const float* __restrict__ pW2,
                         const float* __restrict__ pb2, const float* __restrict__ aW1,
                         const float* __restrict__ ab1, const float* __restrict__ aW2,
                         unsigned char* __restrict__ bext8, unsigned char* __restrict__ aw2f8,
                         unsigned short* __restrict__ pw2f, float* __restrict__ cArr,
                         unsigned char* __restrict__ kN8, float* __restrict__ vPT,
                         float* __restrict__ aI, unsigned short* __restrict__ aJ,
                         float* __restrict__ qa)
{
    __shared__ float s1[4][64];
    __shared__ float s2[4][64];
    const int b = blockIdx.x;
    if (b < 128) {
        // fp8 B_ext frags for G1 mfma_scale 16x16x128.
        const int r = b * 256 + threadIdx.x;  // < 32768
        const int frag = r >> 11, lane = (r >> 5) & 63, e = r & 31;
        const int w = frag >> 2, nt = frag & 3;
        const int tl = lane & 15, qq = lane >> 4;
        const int k = qq * 32 + e;
        const int t = 64 * w + 16 * nt + tl;
        float val;
        if (k < 64) {
            float s = 0.f;
            for (int d = 0; d < 64; ++d) s = fmaf(pW2[k * 64 + d], aW1[d * 256 + t], s);
            val = s;
        } else {
            val = aW1[(k - 64) * 256 + t];
        }
        bext8[r] = f2fp8(val);
    } else if (b < 192) {
        // aW2*log2e fp8 frags for G2 mfma_scale 16x16x128 (R9-verified)
        const int r = (b - 128) * 256 + threadIdx.x;  // < 16384
        const int e = r & 31, lane = (r >> 5) & 63, wsl = (r >> 11) & 3, kb = r >> 13;
        const int q = lane >> 4, dl = lane & 15;
        const int kp = kb * 128 + q * 32 + e;
        const int t = 64 * (kp >> 6) + 16 * (kp & 3) + ((kp >> 2) & 15);
        const int d = 16 * wsl + dl;
        aw2f8[r] = f2fp8(aW2[t * 64 + d] * 1.4426950408889634f);
    } else if (b < 208) {
        // pW2 bf16 frags for G3 (R2-verified)
        const int r = (b - 192) * 256 + threadIdx.x;  // < 4096
        const int k = r >> 6, d = r & 63;
        const int kc = k >> 5, kl = k & 31, qq = kl >> 3, e = kl & 7;
        const int nt = d >> 4, dl = d & 15;
        pw2f[(((size_t)(kc * 4 + nt) * 64) + (qq * 16 + dl)) * 8 + e] = f2b_rne(pW2[k * 64 + d]);
    } else if (b == 208) {
        const int t = threadIdx.x;
        float s = ab1[t];
        for (int d = 0; d < 64; ++d) s = fmaf(pb2[d], aW1[d * 256 + t], s);
        cArr[t] = s;
    } else if (b < 465) {
        // per-point prep: k(fp8), v, aI, aJ — 4 points per block
        const int t = threadIdx.x, sub = t >> 6, d = t & 63;
        const int i = (b - 209) * 4 + sub;
        s1[sub][d] = x[i * 64 + d];
        __syncthreads();
        float k = 0.f, v = 0.f;
        for (int e = 0; e < 64; ++e) {
            const float xe = s1[sub][e];
            k = fmaf(xe, Wk[e * 64 + d], k);
            v = fmaf(xe, Wv[e * 64 + d], v);
        }
        const float a = pos[i * 2] * pW1[d] + pos[i * 2 + 1] * pW1[64 + d];
        kN8[i * 64 + d] = f2fp8(-k);
        vPT[d * NPTS + i] = v + pb2[d];
        aI[i * 64 + d] = a + pb1[d];
        aJ[i * 64 + d] = f2b_rne(a);
    } else {
        // QA[i][t] = (x_i@Wq)@aW1, f32 (per-block-constant fold in main)
        const int i = b - 465, t = threadIdx.x;
        if (t < 64) s1[0][t] = x[i * 64 + t];
        __syncthreads();
        if (t < 64) {
            float s = 0.f;
            for (int e = 0; e < 64; ++e) s = fmaf(s1[0][e], Wq[e * 64 + t], s);
            s2[0][t] = s;
        }
        __syncthreads();
        float s = 0.f;
        for (int d = 0; d < 64; ++d) s = fmaf(s2[0][d], aW1[d * 256 + t], s);
        qa[(size_t)i * 256 + t] = s;
    }
}

// ---------------- main fused kernel: one block per query i, j-tile 32 ----------------
__global__ __launch_bounds__(256, 3) void ptl_main(
    const float* __restrict__ aI, const unsigned short* __restrict__ aJ,
    const unsigned char* __restrict__ kN8, const float* __restrict__ vPT,
    const unsigned char* __restrict__ bext8, const unsigned char* __restrict__ aw2f8,
    const unsigned short* __restrict__ pw2f, const float* __restrict__ cArr,
    const float* __restrict__ qa, float* __restrict__ out)
{
    const int i    = blockIdx.x;
    const int tid  = threadIdx.x;
    const int w    = tid >> 6;    // wave: t-slice [64w,64w+64) for G1, d-slice [16w,16w+16) for G2/G3
    const int lane = tid & 63;
    const int m    = lane & 15;
    const int q    = lane >> 4;

    // double-buffered LDS:
    //   AfL (bf16 relu1 frags, G3 only): [buf][sub][half][lane] = 8 KB
    //   Af8 (fp8 A-tile, G1): [buf][sub][16 rows x 144 stride]  = 9.2 KB
    //   Hs  (fp8 H, G2): stride 272                              = 17.4 KB
    __shared__ __align__(16) uint4 AfL[2][2][2][64];
    __shared__ __align__(16) unsigned char Af8[2][2][16 * 144];
    __shared__ __align__(16) unsigned char Hs[2][2][16 * 272];

    // constant B fragments
    i32x8 B8f[4];  // G1 fp8: [nt 0..3] for this wave's t-slice
#pragma unroll
    for (int nt = 0; nt < 4; ++nt)
        B8f[nt] = ld32B(bext8 + ((size_t)((4 * w + nt) * 64 + lane)) * 32);
    i32x8 W2f[2];  // G2 fp8: [kb 0..1], d-slice w
#pragma unroll
    for (int kb = 0; kb < 2; ++kb)
        W2f[kb] = ld32B(aw2f8 + ((size_t)((kb * 4 + w) * 64 + lane)) * 32);
    sh8 P2f[2];  // G3 bf16: [kc 0..1], d-slice w
#pragma unroll
    for (int kc = 0; kc < 2; ++kc)
        P2f[kc] = *(const sh8*)(pw2f + ((size_t)((kc * 4 + w) * 64 + lane)) * 8);

    float creg[4];  // c + QA_i (both constant over j)
#pragma unroll
    for (int nt = 0; nt < 4; ++nt)
        creg[nt] = cArr[64 * w + 16 * nt + m] + qa[(size_t)i * 256 + 64 * w + 16 * nt + m];

    // builder task: wave w = (sub s_, half h_).  Builds relu1 (bf16 for G3,
    // fp8 for G1) for k-chunk h_, and copies fp8 kN into kpos 64+32h_.
    const int s_ = w >> 1, h_ = w & 1;
    const unsigned short* bsrcA  = aJ  + m * 64 + h_ * 32 + q * 8;
    const unsigned char*  bsrcK8 = kN8 + m * 64 + h_ * 32 + q * 8;
    const float*          ibase  = aI + (size_t)i * 64 + h_ * 32 + q * 8;
    float iv[8];
    *(float4*)(iv)     = *(const float4*)(ibase);
    *(float4*)(iv + 4) = *(const float4*)(ibase + 4);

    // prologue: build tile 0 into buffer 0
    {
        const sh8  rawA  = *(const sh8*)(bsrcA + (size_t)(16 * s_) * 64);
        const uint2 rawK = *(const uint2*)(bsrcK8 + (size_t)(16 * s_) * 64);
        float t[8];
#pragma unroll
        for (int e = 0; e < 8; ++e)
            t[e] = fmaxf(iv[e] - b2f((unsigned short)rawA[e]), 0.f);
        uint4 pk;
        pk.x = pk2(t[0], t[1]); pk.y = pk2(t[2], t[3]);
        pk.z = pk2(t[4], t[5]); pk.w = pk2(t[6], t[7]);
        AfL[0][s_][h_][lane] = pk;
        uint2 f8;
        f8.x = pk4fp8(t[0], t[1], t[2], t[3]);
        f8.y = pk4fp8(t[4], t[5], t[6], t[7]);
        *(uint2*)(Af8[0][s_] + m * 144 + h_ * 32 + q * 8)      = f8;
        *(uint2*)(Af8[0][s_] + m * 144 + 64 + h_ * 32 + q * 8) = rawK;
    }
    __syncthreads();

    float num = 0.f, den = 0.f;
    const f32x4 z4 = {0.f, 0.f, 0.f, 0.f};
    f32x4 aRp0 = z4, aRp1 = z4;   // previous tile's G3 results (pipeline carry)
    const float* vbase = vPT + (size_t)(16 * w + m) * NPTS;

    for (int n = 0; n < 32; ++n) {
        const int pb = n & 1, nb = pb ^ 1;
        const int j0 = n << 5;

        // next tile's raw global loads (this wave's sub/half), issued early
        sh8  rawA;
        uint2 rawK;
        if (n < 31) {
            rawA = *(const sh8*)(bsrcA + (size_t)(j0 + 32 + 16 * s_) * 64);
            rawK = *(const uint2*)(bsrcK8 + (size_t)(j0 + 32 + 16 * s_) * 64);
        }
        // v values for own tile (C-operand of G3)
        const float4 vj0 = *(const float4*)(vbase + j0 + 4 * q);
        const float4 vj1 = *(const float4*)(vbase + j0 + 16 + 4 * q);

        // ---- sub 0: G1 fp8 K=128 (4 mfma_scale) + H-write ----
        {
            const i32x8 A8 = ld32B(Af8[pb][0] + m * 144 + 32 * q);
            f32x4 acc[4];
#pragma unroll
            for (int nt = 0; nt < 4; ++nt) {
                const f32x4 cv = {creg[nt], creg[nt], creg[nt], creg[nt]};
                acc[nt] = __builtin_amdgcn_mfma_scale_f32_16x16x128_f8f6f4(
                    A8, B8f[nt], cv, 0, 0, 0, 127, 0, 127);
            }
            unsigned char* hw = Hs[pb][0] + (4 * q) * 272 + 64 * w + 4 * m;
#pragma unroll
            for (int r = 0; r < 4; ++r)
                *(unsigned*)(hw + r * 272) = pk4fp8(fmaxf(acc[0][r], 0.f), fmaxf(acc[1][r], 0.f),
                                                   fmaxf(acc[2][r], 0.f), fmaxf(acc[3][r], 0.f));
        }

        // ---- deferred-G2 LDS loads for tile n-1 (Hs[nb], published last barrier) ----
        i32x8 h00, h01, h10, h11;
        if (n) {
            h00 = ld32B(Hs[nb][0] + m * 272 + 0   + 32 * q);
            h01 = ld32B(Hs[nb][0] + m * 272 + 128 + 32 * q);
            h10 = ld32B(Hs[nb][1] + m * 272 + 0   + 32 * q);
            h11 = ld32B(Hs[nb][1] + m * 272 + 128 + 32 * q);
        }

        // ---- sub 1: G1 fp8 + H-write ----
        {
            const i32x8 A8 = ld32B(Af8[pb][1] + m * 144 + 32 * q);
            f32x4 acc[4];
#pragma unroll
            for (int nt = 0; nt < 4; ++nt) {
                const f32x4 cv = {creg[nt], creg[nt], creg[nt], creg[nt]};
                acc[nt] = __builtin_amdgcn_mfma_scale_f32_16x16x128_f8f6f4(
                    A8, B8f[nt], cv, 0, 0, 0, 127, 0, 127);
            }
            unsigned char* hw = Hs[pb][1] + (4 * q) * 272 + 64 * w + 4 * m;
#pragma unroll
            for (int r = 0; r < 4; ++r)
                *(unsigned*)(hw + r * 272) = pk4fp8(fmaxf(acc[0][r], 0.f), fmaxf(acc[1][r], 0.f),
                                                   fmaxf(acc[2][r], 0.f), fmaxf(acc[3][r], 0.f));
        }

        // ---- G3 bf16 A-frag loads (AfL[pb]); latency hidden under G2 ----
        const sh8 A00 = *(const sh8*)&AfL[pb][0][0][lane];
        const sh8 A01 = *(const sh8*)&AfL[pb][0][1][lane];
        const sh8 A10 = *(const sh8*)&AfL[pb][1][0][lane];
        const sh8 A11 = *(const sh8*)&AfL[pb][1][1][lane];

        // ---- deferred G2 for tile n-1: simL2 + softmax accumulation ----
        if (n) {
            f32x4 aS0 = z4, aS1 = z4;
            aS0 = __builtin_amdgcn_mfma_scale_f32_16x16x128_f8f6f4(
                h00, W2f[0], aS0, 0, 0, 0, 127, 0, 127);
            aS0 = __builtin_amdgcn_mfma_scale_f32_16x16x128_f8f6f4(
                h01, W2f[1], aS0, 0, 0, 0, 127, 0, 127);
            aS1 = __builtin_amdgcn_mfma_scale_f32_16x16x128_f8f6f4(
                h10, W2f[0], aS1, 0, 0, 0, 127, 0, 127);
            aS1 = __builtin_amdgcn_mfma_scale_f32_16x16x128_f8f6f4(
                h11, W2f[1], aS1, 0, 0, 0, 127, 0, 127);
#pragma unroll
            for (int r = 0; r < 4; ++r) {
                const float e0 = EXP2(aS0[r]);
                num = fmaf(e0, aRp0[r], num);
                den += e0;
                const float e1 = EXP2(aS1[r]);
                num = fmaf(e1, aRp1[r], num);
                den += e1;
            }
        }

        // ---- G3 (pre-barrier, bf16): rpe + v for tile n, aR carried ----
        const f32x4 vc0 = {vj0.x, vj0.y, vj0.z, vj0.w};
        const f32x4 vc1 = {vj1.x, vj1.y, vj1.z, vj1.w};
        f32x4 aR0 = __builtin_amdgcn_mfma_f32_16x16x32_bf16(A00, P2f[0], vc0, 0, 0, 0);
        aR0 = __builtin_amdgcn_mfma_f32_16x16x32_bf16(A01, P2f[1], aR0, 0, 0, 0);
        f32x4 aR1 = __builtin_amdgcn_mfma_f32_16x16x32_bf16(A10, P2f[0], vc1, 0, 0, 0);
        aR1 = __builtin_amdgcn_mfma_f32_16x16x32_bf16(A11, P2f[1], aR1, 0, 0, 0);
        aRp0 = aR0;
        aRp1 = aR1;

        // build next tile's frags: relu1 (bf16+fp8) + fp8 kN copy
        if (n < 31) {
            float t[8];
#pragma unroll
            for (int e = 0; e < 8; ++e)
                t[e] = fmaxf(iv[e] - b2f((unsigned short)rawA[e]), 0.f);
            uint4 pk;
            pk.x = pk2(t[0], t[1]); pk.y = pk2(t[2], t[3]);
            pk.z = pk2(t[4], t[5]); pk.w = pk2(t[6], t[7]);
            AfL[nb][s_][h_][lane] = pk;
            uint2 f8;
            f8.x = pk4fp8(t[0], t[1], t[2], t[3]);
            f8.y = pk4fp8(t[4], t[5], t[6], t[7]);
            *(uint2*)(Af8[nb][s_] + m * 144 + h_ * 32 + q * 8)      = f8;
            *(uint2*)(Af8[nb][s_] + m * 144 + 64 + h_ * 32 + q * 8) = rawK;
        }

        __syncthreads();  // publishes Hs[pb][*] (G2 next iter), AfL/Af8[nb][*]
    }

    // ---- epilogue: deferred G2 for the final tile (buffer 1, published above) ----
    {
        f32x4 aS0 = z4, aS1 = z4;
        const i32x8 h00 = ld32B(Hs[1][0] + m * 272 + 0   + 32 * q);
        const i32x8 h01 = ld32B(Hs[1][0] + m * 272 + 128 + 32 * q);
        const i32x8 h10 = ld32B(Hs[1][1] + m * 272 + 0   + 32 * q);
        const i32x8 h11 = ld32B(Hs[1][1] + m * 272 + 128 + 32 * q);
        aS0 = __builtin_amdgcn_mfma_scale_f32_16x16x128_f8f6f4(
            h00, W2f[0], aS0, 0, 0, 0, 127, 0, 127);
        aS0 = __builtin_amdgcn_mfma_scale_f32_16x16x128_f8f6f4(
            h01, W2f[1], aS0, 0, 0, 0, 127, 0, 127);
        aS1 = __builtin_amdgcn_mfma_scale_f32_16x16x128_f8f6f4(
            h10, W2f[0], aS1, 0, 0, 0, 127, 0, 127);
        aS1 = __builtin_amdgcn_mfma_scale_f32_16x16x128_f8f6f4(
            h11, W2f[1], aS1, 0, 0, 0, 127, 0, 127);
#pragma unroll
        for (int r = 0; r < 4; ++r) {
            const float e0 = EXP2(aS0[r]);
            num = fmaf(e0, aRp0[r], num);
            den += e0;
            const float e1 = EXP2(aS1[r]);
            num = fmaf(e1, aRp1[r], num);
            den += e1;
        }
    }

    // reduce the 4 quad-partials (lanes m, m+16, m+32, m+48)
    num += __shfl_xor(num, 16);
    num += __shfl_xor(num, 32);
    den += __shfl_xor(den, 16);
    den += __shfl_xor(den, 32);
    if (q == 0) out[i * 64 + 16 * w + m] = num / den;
}

extern "C" void kernel_launch(void* const* d_in, const int* in_sizes, int n_in,
                              void* d_out, int out_size, void* d_ws, size_t ws_size,
                              hipStream_t stream) {
    const float* x   = (const float*)d_in[0];
    const float* pos = (const float*)d_in[1];
    const float* Wq  = (const float*)d_in[2];
    const float* Wk  = (const float*)d_in[3];
    const float* Wv  = (const float*)d_in[4];
    const float* pW1 = (const float*)d_in[5];
    const float* pb1 = (const float*)d_in[6];
    const float* pW2 = (const float*)d_in[7];
    const float* pb2 = (const float*)d_in[8];
    const float* aW1 = (const float*)d_in[9];
    const float* ab1 = (const float*)d_in[10];
    const float* aW2 = (const float*)d_in[11];
    // d_in[12] = ab2: constant over j -> cancels in per-channel softmax, unused.

    char* ws = (char*)d_ws;
    unsigned char*  bext8 = (unsigned char*)(ws + BEXT8_OFF);
    unsigned char*  aw2f8 = (unsigned char*)(ws + AW2F_OFF);
    unsigned short* pw2f  = (unsigned short*)(ws + PW2F_OFF);
    float*          cArr  = (float*)(ws + CARR_OFF);
    float*          aIa   = (float*)(ws + AI_OFF);
    float*          vPTa  = (float*)(ws + VPT_OFF);
    unsigned short* aJa   = (unsigned short*)(ws + AJ_OFF);
    unsigned char*  kN8a  = (unsigned char*)(ws + KN8_OFF);
    float*          qaA   = (float*)(ws + QA_OFF);

    prep_all<<<1489, 256, 0, stream>>>(x, pos, Wq, Wk, Wv, pW1, pb1, pW2, pb2, aW1, ab1, aW2,
                                       bext8, aw2f8, pw2f, cArr, kN8a, vPTa, aIa, aJa, qaA);
    ptl_main<<<NPTS, 256, 0, stream>>>(aIa, aJa, kN8a, vPTa, bext8, aw2f8, pw2f, cArr, qaA,
                                       (float*)d_out);
}